// Round 1
// baseline (1207.058 us; speedup 1.0000x reference)
//
#include <hip/hip_runtime.h>
#include <float.h>
#include <math.h>

#define ROWS 8192     // B*S
#define NF   10000    // n_fillers

// ---------------- row squared-norms of a (nrows x 256) f32 matrix ----------------
__global__ __launch_bounds__(256) void k_rownorm(const float* __restrict__ mat,
                                                 float* __restrict__ out, int nrows) {
  int row = blockIdx.x * 4 + (threadIdx.x >> 6);
  int lane = threadIdx.x & 63;
  if (row >= nrows) return;
  float4 v = reinterpret_cast<const float4*>(mat + (size_t)row * 256)[lane];
  float s = v.x * v.x + v.y * v.y + v.z * v.z + v.w * v.w;
  #pragma unroll
  for (int off = 32; off >= 1; off >>= 1) s += __shfl_xor(s, off, 64);
  if (lane == 0) out[row] = s;
}

// ---------------- GEMM1: ht[b, r*256+f] = sum_k hidden[b,k]*W[f*256+r,k] + bias[f*256+r]
// grid 512: block owns n' = r*256+f for n' in [bx*128, bx*128+128)  (fixed r)
__global__ __launch_bounds__(256) void k_gemm1(const float* __restrict__ hidden,
                                               const float* __restrict__ W,
                                               const float* __restrict__ bias,
                                               float* __restrict__ ht) {
  __shared__ float As[64][68];    // [k][b]
  __shared__ float Bs[64][136];   // [k][n_local]
  __shared__ float biasS[128];
  const int tid = threadIdx.x;
  const int nbase = blockIdx.x * 128;
  const int r = nbase >> 8;
  const int f0 = nbase & 255;
  const int tm = tid >> 4, tn = tid & 15;
  const int m0 = tm * 4, n0 = tn * 8;

  if (tid < 128) biasS[tid] = bias[(size_t)(f0 + tid) * 256 + r];

  float acc[4][8];
  #pragma unroll
  for (int i = 0; i < 4; ++i)
    #pragma unroll
    for (int j = 0; j < 8; ++j) acc[i][j] = 0.f;

  for (int kt = 0; kt < 16; ++kt) {
    __syncthreads();
    // stage A: 64 b x 64 k (coalesced k-contig loads, transposed LDS write)
    #pragma unroll
    for (int i = 0; i < 4; ++i) {
      int q = tid + i * 256;              // 1024 quads
      int b = q >> 4, kq = q & 15;
      float4 v = *reinterpret_cast<const float4*>(hidden + (size_t)b * 1024 + kt * 64 + kq * 4);
      As[kq * 4 + 0][b] = v.x;
      As[kq * 4 + 1][b] = v.y;
      As[kq * 4 + 2][b] = v.z;
      As[kq * 4 + 3][b] = v.w;
    }
    // stage B: 128 n x 64 k, w_row = (f0+nl)*256 + r
    #pragma unroll
    for (int i = 0; i < 8; ++i) {
      int q = tid + i * 256;              // 2048 quads
      int nl = q >> 4, kq = q & 15;
      size_t wrow = (size_t)(f0 + nl) * 256 + r;
      float4 v = *reinterpret_cast<const float4*>(W + wrow * 1024 + kt * 64 + kq * 4);
      Bs[kq * 4 + 0][nl] = v.x;
      Bs[kq * 4 + 1][nl] = v.y;
      Bs[kq * 4 + 2][nl] = v.z;
      Bs[kq * 4 + 3][nl] = v.w;
    }
    __syncthreads();
    #pragma unroll
    for (int kk = 0; kk < 64; ++kk) {
      float4 a  = *reinterpret_cast<const float4*>(&As[kk][m0]);
      float4 b0 = *reinterpret_cast<const float4*>(&Bs[kk][n0]);
      float4 b1 = *reinterpret_cast<const float4*>(&Bs[kk][n0 + 4]);
      float av[4] = {a.x, a.y, a.z, a.w};
      float bv[8] = {b0.x, b0.y, b0.z, b0.w, b1.x, b1.y, b1.z, b1.w};
      #pragma unroll
      for (int i = 0; i < 4; ++i)
        #pragma unroll
        for (int j = 0; j < 8; ++j) acc[i][j] += av[i] * bv[j];
    }
  }
  #pragma unroll
  for (int i = 0; i < 4; ++i) {
    int b = m0 + i;
    float4 o0 = make_float4(acc[i][0] + biasS[n0 + 0], acc[i][1] + biasS[n0 + 1],
                            acc[i][2] + biasS[n0 + 2], acc[i][3] + biasS[n0 + 3]);
    float4 o1 = make_float4(acc[i][4] + biasS[n0 + 4], acc[i][5] + biasS[n0 + 5],
                            acc[i][6] + biasS[n0 + 6], acc[i][7] + biasS[n0 + 7]);
    float* p = ht + (size_t)b * 65536 + nbase + n0;
    *reinterpret_cast<float4*>(p)     = o0;
    *reinterpret_cast<float4*>(p + 4) = o1;
  }
}

// ---------------- fg[b,s,f] = sum_r roleE[roles[b,s]][r] * ht[b][r][f]
// grid 256: bx = b*4 + s_quarter; C = 32 s x 256 f
__global__ __launch_bounds__(256) void k_fg(const int* __restrict__ roles,
                                            const float* __restrict__ role_emb,
                                            const float* __restrict__ ht,
                                            float* __restrict__ fg) {
  __shared__ float As[64][40];     // [r][s], 32 s
  __shared__ float Bs[64][264];    // [r][f]
  __shared__ int sidx[32];
  const int tid = threadIdx.x;
  const int b = blockIdx.x >> 2;
  const int sbase = (blockIdx.x & 3) * 32;
  const int tm = tid >> 5, tn = tid & 31;
  const int m0 = tm * 4, n0 = tn * 8;
  if (tid < 32) sidx[tid] = roles[b * 128 + sbase + tid];

  float acc[4][8];
  #pragma unroll
  for (int i = 0; i < 4; ++i)
    #pragma unroll
    for (int j = 0; j < 8; ++j) acc[i][j] = 0.f;

  for (int kt = 0; kt < 4; ++kt) {
    __syncthreads();
    // A: 32 s x 64 r (gathered role rows), transposed write
    #pragma unroll
    for (int i = 0; i < 2; ++i) {
      int q = tid + i * 256;              // 512 quads
      int s = q >> 4, rq = q & 15;
      float4 v = *reinterpret_cast<const float4*>(role_emb + (size_t)sidx[s] * 256 + kt * 64 + rq * 4);
      As[rq * 4 + 0][s] = v.x;
      As[rq * 4 + 1][s] = v.y;
      As[rq * 4 + 2][s] = v.z;
      As[rq * 4 + 3][s] = v.w;
    }
    // B: 64 r x 256 f, direct copy (already [r][f])
    #pragma unroll
    for (int i = 0; i < 16; ++i) {
      int q = tid + i * 256;              // 4096 quads
      int rr = q >> 6, fq = q & 63;
      float4 v = *reinterpret_cast<const float4*>(ht + (size_t)b * 65536 + (size_t)(kt * 64 + rr) * 256 + fq * 4);
      *reinterpret_cast<float4*>(&Bs[rr][fq * 4]) = v;
    }
    __syncthreads();
    #pragma unroll
    for (int kk = 0; kk < 64; ++kk) {
      float4 a  = *reinterpret_cast<const float4*>(&As[kk][m0]);
      float4 b0 = *reinterpret_cast<const float4*>(&Bs[kk][n0]);
      float4 b1 = *reinterpret_cast<const float4*>(&Bs[kk][n0 + 4]);
      float av[4] = {a.x, a.y, a.z, a.w};
      float bv[8] = {b0.x, b0.y, b0.z, b0.w, b1.x, b1.y, b1.z, b1.w};
      #pragma unroll
      for (int i = 0; i < 4; ++i)
        #pragma unroll
        for (int j = 0; j < 8; ++j) acc[i][j] += av[i] * bv[j];
    }
  }
  #pragma unroll
  for (int i = 0; i < 4; ++i) {
    float* p = fg + (size_t)(b * 128 + sbase + m0 + i) * 256 + n0;
    *reinterpret_cast<float4*>(p)     = make_float4(acc[i][0], acc[i][1], acc[i][2], acc[i][3]);
    *reinterpret_cast<float4*>(p + 4) = make_float4(acc[i][4], acc[i][5], acc[i][6], acc[i][7]);
  }
}

// ---------------- fused distance GEMM + online softmax stats + dist store
// grid 256: bx = rowblk*2 + half; 64 rows x 5000 cols per block; 512 threads
__global__ __launch_bounds__(512) void k_dist(const float* __restrict__ fg,
                                              const float* __restrict__ filler,
                                              const float* __restrict__ fgn,
                                              const float* __restrict__ fln,
                                              float* __restrict__ out,
                                              float* __restrict__ parts) {
  __shared__ float As[256][68];   // [k][m], full K resident
  __shared__ float Bs[32][264];   // [k][n]
  __shared__ float rn2[64];
  __shared__ float cn2[256];
  const int tid = threadIdx.x;
  const int rb = blockIdx.x >> 1, half = blockIdx.x & 1;
  const int rbase = rb * 64;
  const int nbase0 = half * 5000;

  #pragma unroll
  for (int i = 0; i < 8; ++i) {
    int q = tid + i * 512;                 // 4096 quads
    int m = q >> 6, kq = q & 63;
    float4 v = *reinterpret_cast<const float4*>(fg + (size_t)(rbase + m) * 256 + kq * 4);
    As[kq * 4 + 0][m] = v.x;
    As[kq * 4 + 1][m] = v.y;
    As[kq * 4 + 2][m] = v.z;
    As[kq * 4 + 3][m] = v.w;
  }
  if (tid < 64) rn2[tid] = fgn[rbase + tid];

  const int tm = tid >> 5, tn = tid & 31;
  const int m0 = tm * 4, n0 = tn * 8;
  float mv[4], sv[4], bestd[4];
  int bestn[4];
  #pragma unroll
  for (int i = 0; i < 4; ++i) { mv[i] = FLT_MAX; sv[i] = 0.f; bestd[i] = FLT_MAX; bestn[i] = 0; }

  for (int nc = 0; nc < 20; ++nc) {
    const int nbase = nbase0 + nc * 256;
    const int valid = min(256, nbase0 + 5000 - nbase);   // 256 or 136 (both %8==0)
    __syncthreads();   // previous-chunk epilogue reads of cn2 done
    if (tid < 64) {
      float4 v = make_float4(0.f, 0.f, 0.f, 0.f);
      if (tid * 4 < valid) v = *reinterpret_cast<const float4*>(fln + nbase + tid * 4);
      *reinterpret_cast<float4*>(&cn2[tid * 4]) = v;
    }
    float acc[4][8];
    #pragma unroll
    for (int i = 0; i < 4; ++i)
      #pragma unroll
      for (int j = 0; j < 8; ++j) acc[i][j] = 0.f;

    for (int kt = 0; kt < 8; ++kt) {
      __syncthreads();
      #pragma unroll
      for (int i = 0; i < 4; ++i) {
        int q = tid + i * 512;             // 2048 quads
        int n = q >> 3, kq = q & 7;
        float4 v = make_float4(0.f, 0.f, 0.f, 0.f);
        if (n < valid)
          v = *reinterpret_cast<const float4*>(filler + (size_t)(nbase + n) * 256 + kt * 32 + kq * 4);
        Bs[kq * 4 + 0][n] = v.x;
        Bs[kq * 4 + 1][n] = v.y;
        Bs[kq * 4 + 2][n] = v.z;
        Bs[kq * 4 + 3][n] = v.w;
      }
      __syncthreads();
      #pragma unroll
      for (int kk = 0; kk < 32; ++kk) {
        float4 a  = *reinterpret_cast<const float4*>(&As[kt * 32 + kk][m0]);
        float4 b0 = *reinterpret_cast<const float4*>(&Bs[kk][n0]);
        float4 b1 = *reinterpret_cast<const float4*>(&Bs[kk][n0 + 4]);
        float av[4] = {a.x, a.y, a.z, a.w};
        float bv[8] = {b0.x, b0.y, b0.z, b0.w, b1.x, b1.y, b1.z, b1.w};
        #pragma unroll
        for (int i = 0; i < 4; ++i)
          #pragma unroll
          for (int j = 0; j < 8; ++j) acc[i][j] += av[i] * bv[j];
      }
    }
    // per-chunk epilogue: dist, store, online stats
    if (n0 + 8 <= valid) {
      #pragma unroll
      for (int i = 0; i < 4; ++i) {
        float r2 = rn2[m0 + i];
        float d[8];
        #pragma unroll
        for (int j = 0; j < 8; ++j) {
          float d2 = r2 - 2.f * acc[i][j] + cn2[n0 + j];
          d[j] = sqrtf(fmaxf(d2, 0.f));
        }
        float* p = out + (size_t)(rbase + m0 + i) * NF + nbase + n0;
        *reinterpret_cast<float4*>(p)     = make_float4(d[0], d[1], d[2], d[3]);
        *reinterpret_cast<float4*>(p + 4) = make_float4(d[4], d[5], d[6], d[7]);
        float cmin = d[0];
        #pragma unroll
        for (int j = 1; j < 8; ++j) cmin = fminf(cmin, d[j]);
        float mnew = fminf(mv[i], cmin);
        float ssum = sv[i] * __expf(mnew - mv[i]);
        #pragma unroll
        for (int j = 0; j < 8; ++j) ssum += __expf(mnew - d[j]);
        sv[i] = ssum; mv[i] = mnew;
        #pragma unroll
        for (int j = 0; j < 8; ++j)
          if (d[j] < bestd[i]) { bestd[i] = d[j]; bestn[i] = nbase + n0 + j; }
      }
    }
  }

  // block-level reduce across the 32 n-groups (reuse Bs as scratch: 8448 >= 8192 floats)
  __syncthreads();
  float* redM = &Bs[0][0];
  float* redS = redM + 2048;
  float* redD = redM + 4096;
  float* redN = redM + 6144;
  #pragma unroll
  for (int i = 0; i < 4; ++i) {
    int row = m0 + i;
    redM[row * 32 + tn] = mv[i];
    redS[row * 32 + tn] = sv[i];
    redD[row * 32 + tn] = bestd[i];
    redN[row * 32 + tn] = (float)bestn[i];
  }
  __syncthreads();
  if (tid < 64) {
    int row = tid;
    float m = FLT_MAX;
    for (int t = 0; t < 32; ++t) m = fminf(m, redM[row * 32 + t]);
    float S = 0.f;
    for (int t = 0; t < 32; ++t) S += redS[row * 32 + t] * __expf(m - redM[row * 32 + t]);
    float bd = FLT_MAX, bn = 0.f;
    for (int t = 0; t < 32; ++t) {
      float dd = redD[row * 32 + t], nn = redN[row * 32 + t];
      if (dd < bd || (dd == bd && nn < bn)) { bd = dd; bn = nn; }
    }
    float* p = parts + ((size_t)(rbase + row) * 2 + half) * 4;
    p[0] = m; p[1] = S; p[2] = bd; p[3] = bn;
  }
}

// ---------------- combine the 2 n-halves per row -> LSE + preds ----------------
__global__ __launch_bounds__(256) void k_combine(const float* __restrict__ parts,
                                                 float* __restrict__ lse,
                                                 float* __restrict__ preds) {
  int row = blockIdx.x * 256 + threadIdx.x;
  if (row >= ROWS) return;
  const float* p = parts + (size_t)row * 8;
  float m0 = p[0], s0 = p[1], d0 = p[2], n0 = p[3];
  float m1 = p[4], s1 = p[5], d1 = p[6], n1 = p[7];
  float m = fminf(m0, m1);
  float S = s0 * __expf(m - m0) + s1 * __expf(m - m1);
  lse[row] = logf(S) - m;              // logsumexp of (-dist)
  preds[row] = (d1 < d0 || (d1 == d0 && n1 < n0)) ? n1 : n0;
}

// ---------------- in-place: logp = -dist - LSE[row] ----------------
__global__ __launch_bounds__(256) void k_epilogue(float* __restrict__ out,
                                                  const float* __restrict__ lse) {
  int row = blockIdx.y;
  int c4 = blockIdx.x * 256 + threadIdx.x;   // 2500 float4s per row
  if (c4 >= 2500) return;
  float L = lse[row];
  float4* p = reinterpret_cast<float4*>(out + (size_t)row * NF) + c4;
  float4 v = *p;
  v.x = -v.x - L; v.y = -v.y - L; v.z = -v.z - L; v.w = -v.w - L;
  *p = v;
}

extern "C" void kernel_launch(void* const* d_in, const int* in_sizes, int n_in,
                              void* d_out, int out_size, void* d_ws, size_t ws_size,
                              hipStream_t stream) {
  const int*   roles   = (const int*)d_in[0];
  const float* hidden  = (const float*)d_in[1];
  const float* filler  = (const float*)d_in[2];
  const float* roleemb = (const float*)d_in[3];
  const float* W       = (const float*)d_in[4];
  const float* bias    = (const float*)d_in[5];
  float* out = (float*)d_out;

  float* ws    = (float*)d_ws;
  float* ht    = ws;                    // 4,194,304 f32  (64 x 256r x 256f)
  float* fg    = ht + 4194304;          // 2,097,152 f32  (8192 x 256)
  float* fgn   = fg + 2097152;          // 8192
  float* fln   = fgn + 8192;            // 10000 (pad to 10240)
  float* parts = fln + 10240;           // 8192 x 2 x 4
  float* lse   = parts + 65536;         // 8192

  k_rownorm<<<2500, 256, 0, stream>>>(filler, fln, NF);
  k_gemm1<<<512, 256, 0, stream>>>(hidden, W, bias, ht);
  k_fg<<<256, 256, 0, stream>>>(roles, roleemb, ht, fg);
  k_rownorm<<<2048, 256, 0, stream>>>(fg, fgn, ROWS);
  k_dist<<<256, 512, 0, stream>>>(fg, filler, fgn, fln, out, parts);
  k_combine<<<32, 256, 0, stream>>>(parts, lse, out + (size_t)ROWS * NF);
  k_epilogue<<<dim3(10, 8192), 256, 0, stream>>>(out, lse);
}

// Round 2
// 930.392 us; speedup vs baseline: 1.2974x; 1.2974x over previous
//
#include <hip/hip_runtime.h>
#include <float.h>
#include <math.h>

#define ROWS 8192     // B*S
#define NF   10000    // n_fillers

// ---------------- row squared-norms of a (nrows x 256) f32 matrix ----------------
__global__ __launch_bounds__(256) void k_rownorm(const float* __restrict__ mat,
                                                 float* __restrict__ out, int nrows) {
  int row = blockIdx.x * 4 + (threadIdx.x >> 6);
  int lane = threadIdx.x & 63;
  if (row >= nrows) return;
  float4 v = reinterpret_cast<const float4*>(mat + (size_t)row * 256)[lane];
  float s = v.x * v.x + v.y * v.y + v.z * v.z + v.w * v.w;
  #pragma unroll
  for (int off = 32; off >= 1; off >>= 1) s += __shfl_xor(s, off, 64);
  if (lane == 0) out[row] = s;
}

// ---------------- GEMM1: ht[b, r*256+f] = sum_k hidden[b,k]*W[f*256+r,k] + bias[f*256+r]
__global__ __launch_bounds__(256) void k_gemm1(const float* __restrict__ hidden,
                                               const float* __restrict__ W,
                                               const float* __restrict__ bias,
                                               float* __restrict__ ht) {
  __shared__ float As[64][68];    // [k][b]
  __shared__ float Bs[64][136];   // [k][n_local]
  __shared__ float biasS[128];
  const int tid = threadIdx.x;
  const int nbase = blockIdx.x * 128;
  const int r = nbase >> 8;
  const int f0 = nbase & 255;
  const int tm = tid >> 4, tn = tid & 15;
  const int m0 = tm * 4, n0 = tn * 8;

  if (tid < 128) biasS[tid] = bias[(size_t)(f0 + tid) * 256 + r];

  float acc[4][8];
  #pragma unroll
  for (int i = 0; i < 4; ++i)
    #pragma unroll
    for (int j = 0; j < 8; ++j) acc[i][j] = 0.f;

  for (int kt = 0; kt < 16; ++kt) {
    __syncthreads();
    #pragma unroll
    for (int i = 0; i < 4; ++i) {
      int q = tid + i * 256;
      int b = q >> 4, kq = q & 15;
      float4 v = *reinterpret_cast<const float4*>(hidden + (size_t)b * 1024 + kt * 64 + kq * 4);
      As[kq * 4 + 0][b] = v.x;
      As[kq * 4 + 1][b] = v.y;
      As[kq * 4 + 2][b] = v.z;
      As[kq * 4 + 3][b] = v.w;
    }
    #pragma unroll
    for (int i = 0; i < 8; ++i) {
      int q = tid + i * 256;
      int nl = q >> 4, kq = q & 15;
      size_t wrow = (size_t)(f0 + nl) * 256 + r;
      float4 v = *reinterpret_cast<const float4*>(W + wrow * 1024 + kt * 64 + kq * 4);
      Bs[kq * 4 + 0][nl] = v.x;
      Bs[kq * 4 + 1][nl] = v.y;
      Bs[kq * 4 + 2][nl] = v.z;
      Bs[kq * 4 + 3][nl] = v.w;
    }
    __syncthreads();
    #pragma unroll
    for (int kk = 0; kk < 64; ++kk) {
      float4 a  = *reinterpret_cast<const float4*>(&As[kk][m0]);
      float4 b0 = *reinterpret_cast<const float4*>(&Bs[kk][n0]);
      float4 b1 = *reinterpret_cast<const float4*>(&Bs[kk][n0 + 4]);
      float av[4] = {a.x, a.y, a.z, a.w};
      float bv[8] = {b0.x, b0.y, b0.z, b0.w, b1.x, b1.y, b1.z, b1.w};
      #pragma unroll
      for (int i = 0; i < 4; ++i)
        #pragma unroll
        for (int j = 0; j < 8; ++j) acc[i][j] += av[i] * bv[j];
    }
  }
  #pragma unroll
  for (int i = 0; i < 4; ++i) {
    int b = m0 + i;
    float4 o0 = make_float4(acc[i][0] + biasS[n0 + 0], acc[i][1] + biasS[n0 + 1],
                            acc[i][2] + biasS[n0 + 2], acc[i][3] + biasS[n0 + 3]);
    float4 o1 = make_float4(acc[i][4] + biasS[n0 + 4], acc[i][5] + biasS[n0 + 5],
                            acc[i][6] + biasS[n0 + 6], acc[i][7] + biasS[n0 + 7]);
    float* p = ht + (size_t)b * 65536 + nbase + n0;
    *reinterpret_cast<float4*>(p)     = o0;
    *reinterpret_cast<float4*>(p + 4) = o1;
  }
}

// ---------------- fg[b,s,f] = sum_r roleE[roles[b,s]][r] * ht[b][r][f]
__global__ __launch_bounds__(256) void k_fg(const int* __restrict__ roles,
                                            const float* __restrict__ role_emb,
                                            const float* __restrict__ ht,
                                            float* __restrict__ fg) {
  __shared__ float As[64][40];
  __shared__ float Bs[64][264];
  __shared__ int sidx[32];
  const int tid = threadIdx.x;
  const int b = blockIdx.x >> 2;
  const int sbase = (blockIdx.x & 3) * 32;
  const int tm = tid >> 5, tn = tid & 31;
  const int m0 = tm * 4, n0 = tn * 8;
  if (tid < 32) sidx[tid] = roles[b * 128 + sbase + tid];

  float acc[4][8];
  #pragma unroll
  for (int i = 0; i < 4; ++i)
    #pragma unroll
    for (int j = 0; j < 8; ++j) acc[i][j] = 0.f;

  for (int kt = 0; kt < 4; ++kt) {
    __syncthreads();
    #pragma unroll
    for (int i = 0; i < 2; ++i) {
      int q = tid + i * 256;
      int s = q >> 4, rq = q & 15;
      float4 v = *reinterpret_cast<const float4*>(role_emb + (size_t)sidx[s] * 256 + kt * 64 + rq * 4);
      As[rq * 4 + 0][s] = v.x;
      As[rq * 4 + 1][s] = v.y;
      As[rq * 4 + 2][s] = v.z;
      As[rq * 4 + 3][s] = v.w;
    }
    #pragma unroll
    for (int i = 0; i < 16; ++i) {
      int q = tid + i * 256;
      int rr = q >> 6, fq = q & 63;
      float4 v = *reinterpret_cast<const float4*>(ht + (size_t)b * 65536 + (size_t)(kt * 64 + rr) * 256 + fq * 4);
      *reinterpret_cast<float4*>(&Bs[rr][fq * 4]) = v;
    }
    __syncthreads();
    #pragma unroll
    for (int kk = 0; kk < 64; ++kk) {
      float4 a  = *reinterpret_cast<const float4*>(&As[kk][m0]);
      float4 b0 = *reinterpret_cast<const float4*>(&Bs[kk][n0]);
      float4 b1 = *reinterpret_cast<const float4*>(&Bs[kk][n0 + 4]);
      float av[4] = {a.x, a.y, a.z, a.w};
      float bv[8] = {b0.x, b0.y, b0.z, b0.w, b1.x, b1.y, b1.z, b1.w};
      #pragma unroll
      for (int i = 0; i < 4; ++i)
        #pragma unroll
        for (int j = 0; j < 8; ++j) acc[i][j] += av[i] * bv[j];
    }
  }
  #pragma unroll
  for (int i = 0; i < 4; ++i) {
    float* p = fg + (size_t)(b * 128 + sbase + m0 + i) * 256 + n0;
    *reinterpret_cast<float4*>(p)     = make_float4(acc[i][0], acc[i][1], acc[i][2], acc[i][3]);
    *reinterpret_cast<float4*>(p + 4) = make_float4(acc[i][4], acc[i][5], acc[i][6], acc[i][7]);
  }
}

// ---------------- fused distance GEMM + online softmax stats + dist store
// grid 1024: bx = strip*128 + rb; block = 64 rows x (strip of 5 x 256 cols); 256 thr
// thread tile 8x8: rows m0..m0+7, cols {tn*4..+3} u {128+tn*4..+3}
// LDS XOR swizzle: element (k, x) stored at col x ^ (((k>>2)&7)<<2)
__global__ __launch_bounds__(256, 3) void k_dist(const float* __restrict__ fg,
                                                 const float* __restrict__ filler,
                                                 const float* __restrict__ fgn,
                                                 const float* __restrict__ fln,
                                                 float* __restrict__ out,
                                                 float* __restrict__ parts) {
  __shared__ float As[32][64];    // [k][m] swizzled
  __shared__ float Bs[32][256];   // [k][n] swizzled
  __shared__ float rn2[64];
  __shared__ float cn2[256];
  const int tid = threadIdx.x;
  const int rb = blockIdx.x & 127;
  const int strip = blockIdx.x >> 7;
  const int rbase = rb * 64;
  const int tm = tid >> 5, tn = tid & 31;
  const int m0 = tm * 8;
  const int c0 = tn * 4, c1 = 128 + tn * 4;

  if (tid < 64) rn2[tid] = fgn[rbase + tid];

  float mv[8], sv[8], bestd[8];
  int bestn[8];
  #pragma unroll
  for (int i = 0; i < 8; ++i) { mv[i] = FLT_MAX; sv[i] = 0.f; bestd[i] = FLT_MAX; bestn[i] = 0; }

  for (int nc = 0; nc < 5; ++nc) {
    const int nbase = strip * 1280 + nc * 256;
    __syncthreads();   // prior epilogue readers of cn2 done
    if (tid < 64) {
      int idx = nbase + tid * 4;
      float4 v;
      if (idx + 4 <= NF) v = *reinterpret_cast<const float4*>(fln + idx);
      else {
        v.x = (idx + 0 < NF) ? fln[idx + 0] : 1e30f;
        v.y = (idx + 1 < NF) ? fln[idx + 1] : 1e30f;
        v.z = (idx + 2 < NF) ? fln[idx + 2] : 1e30f;
        v.w = (idx + 3 < NF) ? fln[idx + 3] : 1e30f;
      }
      *reinterpret_cast<float4*>(&cn2[tid * 4]) = v;
    }
    float acc[8][8];
    #pragma unroll
    for (int i = 0; i < 8; ++i)
      #pragma unroll
      for (int j = 0; j < 8; ++j) acc[i][j] = 0.f;

    for (int kt = 0; kt < 8; ++kt) {
      __syncthreads();
      // stage A: 64 rows x 32 k (2 float4/thread), swizzled transpose write
      #pragma unroll
      for (int i = 0; i < 2; ++i) {
        int q = tid + i * 256;
        int m = q >> 3, kq = q & 7;
        float4 v = *reinterpret_cast<const float4*>(fg + (size_t)(rbase + m) * 256 + kt * 32 + kq * 4);
        int col = m ^ (kq << 2);
        As[kq * 4 + 0][col] = v.x;
        As[kq * 4 + 1][col] = v.y;
        As[kq * 4 + 2][col] = v.z;
        As[kq * 4 + 3][col] = v.w;
      }
      // stage B: 256 cols x 32 k (8 float4/thread), clamped rows, swizzled write
      #pragma unroll
      for (int i = 0; i < 8; ++i) {
        int q = tid + i * 256;
        int n = q >> 3, kq = q & 7;
        int rown = nbase + n; if (rown > NF - 1) rown = NF - 1;
        float4 v = *reinterpret_cast<const float4*>(filler + (size_t)rown * 256 + kt * 32 + kq * 4);
        int col = n ^ (kq << 2);
        Bs[kq * 4 + 0][col] = v.x;
        Bs[kq * 4 + 1][col] = v.y;
        Bs[kq * 4 + 2][col] = v.z;
        Bs[kq * 4 + 3][col] = v.w;
      }
      __syncthreads();
      #pragma unroll
      for (int kk = 0; kk < 32; ++kk) {
        const int msk = (kk >> 2) << 2;
        float4 a0 = *reinterpret_cast<const float4*>(&As[kk][m0 ^ msk]);
        float4 a1 = *reinterpret_cast<const float4*>(&As[kk][(m0 + 4) ^ msk]);
        float4 b0 = *reinterpret_cast<const float4*>(&Bs[kk][c0 ^ msk]);
        float4 b1 = *reinterpret_cast<const float4*>(&Bs[kk][c1 ^ msk]);
        float av[8] = {a0.x, a0.y, a0.z, a0.w, a1.x, a1.y, a1.z, a1.w};
        float bv[8] = {b0.x, b0.y, b0.z, b0.w, b1.x, b1.y, b1.z, b1.w};
        #pragma unroll
        for (int i = 0; i < 8; ++i)
          #pragma unroll
          for (int j = 0; j < 8; ++j) acc[i][j] += av[i] * bv[j];
      }
    }
    // chunk epilogue: dist, store, online stats
    #pragma unroll
    for (int i = 0; i < 8; ++i) {
      float r2 = rn2[m0 + i];
      float d[8];
      #pragma unroll
      for (int j = 0; j < 4; ++j) d[j]     = sqrtf(fmaxf(r2 - 2.f * acc[i][j]     + cn2[c0 + j], 0.f));
      #pragma unroll
      for (int j = 0; j < 4; ++j) d[4 + j] = sqrtf(fmaxf(r2 - 2.f * acc[i][4 + j] + cn2[c1 + j], 0.f));
      float* prow = out + (size_t)(rbase + m0 + i) * NF + nbase;
      if (nbase + c0 + 4 <= NF)
        *reinterpret_cast<float4*>(prow + c0) = make_float4(d[0], d[1], d[2], d[3]);
      if (nbase + c1 + 4 <= NF)
        *reinterpret_cast<float4*>(prow + c1) = make_float4(d[4], d[5], d[6], d[7]);
      float cmin = d[0];
      #pragma unroll
      for (int j = 1; j < 8; ++j) cmin = fminf(cmin, d[j]);
      float mnew = fminf(mv[i], cmin);
      float ssum = sv[i] * __expf(mnew - mv[i]);
      #pragma unroll
      for (int j = 0; j < 8; ++j) ssum += __expf(mnew - d[j]);
      sv[i] = ssum; mv[i] = mnew;
      #pragma unroll
      for (int j = 0; j < 8; ++j) {
        int col = nbase + ((j < 4) ? (c0 + j) : (c1 + j - 4));
        if (d[j] < bestd[i]) { bestd[i] = d[j]; bestn[i] = col; }
      }
    }
  }

  // block reduce across the 32 n-groups (reuse As/Bs as scratch)
  __syncthreads();
  float* redM = &As[0][0];          // 2048 floats
  float* redS = &Bs[0][0];          // 2048
  float* redD = redS + 2048;        // 2048
  float* redN = redS + 4096;        // 2048
  #pragma unroll
  for (int i = 0; i < 8; ++i) {
    int row = m0 + i;
    redM[row * 32 + tn] = mv[i];
    redS[row * 32 + tn] = sv[i];
    redD[row * 32 + tn] = bestd[i];
    redN[row * 32 + tn] = (float)bestn[i];
  }
  __syncthreads();
  if (tid < 64) {
    int row = tid;
    float m = FLT_MAX;
    for (int t = 0; t < 32; ++t) m = fminf(m, redM[row * 32 + t]);
    float S = 0.f;
    for (int t = 0; t < 32; ++t) S += redS[row * 32 + t] * __expf(m - redM[row * 32 + t]);
    float bd = FLT_MAX, bn = 0.f;
    for (int t = 0; t < 32; ++t) {
      float dd = redD[row * 32 + t], nn = redN[row * 32 + t];
      if (dd < bd || (dd == bd && nn < bn)) { bd = dd; bn = nn; }
    }
    float* p = parts + ((size_t)(rbase + row) * 8 + strip) * 4;
    p[0] = m; p[1] = S; p[2] = bd; p[3] = bn;
  }
}

// ---------------- fused: combine 8 strips -> LSE + preds, then logp = -d - LSE ----------------
__global__ __launch_bounds__(256) void k_final(const float* __restrict__ parts,
                                               float* __restrict__ out) {
  const int row = blockIdx.x;
  __shared__ float shL;
  if (threadIdx.x == 0) {
    const float* p = parts + (size_t)row * 32;
    float m = FLT_MAX;
    #pragma unroll
    for (int s = 0; s < 8; ++s) m = fminf(m, p[s * 4]);
    float S = 0.f;
    #pragma unroll
    for (int s = 0; s < 8; ++s) S += p[s * 4 + 1] * __expf(m - p[s * 4]);
    float bd = FLT_MAX, bn = 0.f;
    #pragma unroll
    for (int s = 0; s < 8; ++s) {
      float dd = p[s * 4 + 2], nn = p[s * 4 + 3];
      if (dd < bd || (dd == bd && nn < bn)) { bd = dd; bn = nn; }
    }
    shL = logf(S) - m;                       // logsumexp of (-dist)
    out[(size_t)ROWS * NF + row] = bn;       // preds
  }
  __syncthreads();
  const float L = shL;
  float4* prow = reinterpret_cast<float4*>(out + (size_t)row * NF);
  for (int c = threadIdx.x; c < 2500; c += 256) {
    float4 v = prow[c];
    v.x = -v.x - L; v.y = -v.y - L; v.z = -v.z - L; v.w = -v.w - L;
    prow[c] = v;
  }
}

extern "C" void kernel_launch(void* const* d_in, const int* in_sizes, int n_in,
                              void* d_out, int out_size, void* d_ws, size_t ws_size,
                              hipStream_t stream) {
  const int*   roles   = (const int*)d_in[0];
  const float* hidden  = (const float*)d_in[1];
  const float* filler  = (const float*)d_in[2];
  const float* roleemb = (const float*)d_in[3];
  const float* W       = (const float*)d_in[4];
  const float* bias    = (const float*)d_in[5];
  float* out = (float*)d_out;

  float* ws    = (float*)d_ws;
  float* ht    = ws;                    // 4,194,304 f32  (64 x 256r x 256f)
  float* fg    = ht + 4194304;          // 2,097,152 f32  (8192 x 256)
  float* fgn   = fg + 2097152;          // 8192
  float* fln   = fgn + 8192;            // 10000 (pad to 10240)
  float* parts = fln + 10240;           // 8192 x 8 x 4

  k_rownorm<<<2500, 256, 0, stream>>>(filler, fln, NF);
  k_gemm1<<<512, 256, 0, stream>>>(hidden, W, bias, ht);
  k_fg<<<256, 256, 0, stream>>>(roles, roleemb, ht, fg);
  k_rownorm<<<2048, 256, 0, stream>>>(fg, fgn, ROWS);
  k_dist<<<1024, 256, 0, stream>>>(fg, filler, fgn, fln, out, parts);
  k_final<<<8192, 256, 0, stream>>>(parts, out);
}

// Round 3
// 735.310 us; speedup vs baseline: 1.6416x; 1.2653x over previous
//
#include <hip/hip_runtime.h>
#include <hip/hip_bf16.h>
#include <float.h>
#include <math.h>

#define ROWS 8192     // B*S
#define NF   10000    // n_fillers
#define NPAD 10112    // 79 * 128

typedef short s8v __attribute__((ext_vector_type(8)));
typedef float f4v __attribute__((ext_vector_type(4)));

#define GLD16(g, l) __builtin_amdgcn_global_load_lds((const __attribute__((address_space(1))) void*)(g), (__attribute__((address_space(3))) void*)(l), 16, 0, 0)

__device__ inline unsigned short f2bf(float x) {
  __hip_bfloat16 h = __float2bfloat16(x);
  return __builtin_bit_cast(unsigned short, h);
}
__device__ inline float bf2f(unsigned short u) {
  __hip_bfloat16 h = __builtin_bit_cast(__hip_bfloat16, u);
  return __bfloat162float(h);
}

// ---------------- filler: row norms + hi/lo bf16 conversion (rows padded to NPAD) ----------------
__global__ __launch_bounds__(256) void k_cvt_filler(const float* __restrict__ filler,
                                                    unsigned short* __restrict__ fl2,
                                                    float* __restrict__ fln) {
  int row = blockIdx.x * 4 + (threadIdx.x >> 6);
  int lane = threadIdx.x & 63;
  if (row >= NPAD) return;
  if (row < NF) {
    float4 v = reinterpret_cast<const float4*>(filler + (size_t)row * 256)[lane];
    float s = v.x * v.x + v.y * v.y + v.z * v.z + v.w * v.w;
    #pragma unroll
    for (int off = 32; off >= 1; off >>= 1) s += __shfl_xor(s, off, 64);
    if (lane == 0) fln[row] = s;
    float xs[4] = {v.x, v.y, v.z, v.w};
    unsigned short h[4], lo[4];
    #pragma unroll
    for (int j = 0; j < 4; ++j) { h[j] = f2bf(xs[j]); lo[j] = f2bf(xs[j] - bf2f(h[j])); }
    uint2 hh = make_uint2(h[0] | ((unsigned)h[1] << 16), h[2] | ((unsigned)h[3] << 16));
    uint2 ll = make_uint2(lo[0] | ((unsigned)lo[1] << 16), lo[2] | ((unsigned)lo[3] << 16));
    *reinterpret_cast<uint2*>(fl2 + (size_t)row * 512 + lane * 4) = hh;
    *reinterpret_cast<uint2*>(fl2 + (size_t)row * 512 + 256 + lane * 4) = ll;
  } else {
    *reinterpret_cast<uint2*>(fl2 + (size_t)row * 512 + lane * 4) = make_uint2(0, 0);
    *reinterpret_cast<uint2*>(fl2 + (size_t)row * 512 + 256 + lane * 4) = make_uint2(0, 0);
    if (lane == 0) fln[row] = 1e30f;
  }
}

// ---------------- GEMM1: ht[b, r*256+f] = sum_k hidden[b,k]*W[f*256+r,k] + bias[f*256+r]
__global__ __launch_bounds__(256) void k_gemm1(const float* __restrict__ hidden,
                                               const float* __restrict__ W,
                                               const float* __restrict__ bias,
                                               float* __restrict__ ht) {
  __shared__ float As[64][68];
  __shared__ float Bs[64][136];
  __shared__ float biasS[128];
  const int tid = threadIdx.x;
  const int nbase = blockIdx.x * 128;
  const int r = nbase >> 8;
  const int f0 = nbase & 255;
  const int tm = tid >> 4, tn = tid & 15;
  const int m0 = tm * 4, n0 = tn * 8;

  if (tid < 128) biasS[tid] = bias[(size_t)(f0 + tid) * 256 + r];

  float acc[4][8];
  #pragma unroll
  for (int i = 0; i < 4; ++i)
    #pragma unroll
    for (int j = 0; j < 8; ++j) acc[i][j] = 0.f;

  for (int kt = 0; kt < 16; ++kt) {
    __syncthreads();
    #pragma unroll
    for (int i = 0; i < 4; ++i) {
      int q = tid + i * 256;
      int b = q >> 4, kq = q & 15;
      float4 v = *reinterpret_cast<const float4*>(hidden + (size_t)b * 1024 + kt * 64 + kq * 4);
      As[kq * 4 + 0][b] = v.x;
      As[kq * 4 + 1][b] = v.y;
      As[kq * 4 + 2][b] = v.z;
      As[kq * 4 + 3][b] = v.w;
    }
    #pragma unroll
    for (int i = 0; i < 8; ++i) {
      int q = tid + i * 256;
      int nl = q >> 4, kq = q & 15;
      size_t wrow = (size_t)(f0 + nl) * 256 + r;
      float4 v = *reinterpret_cast<const float4*>(W + wrow * 1024 + kt * 64 + kq * 4);
      Bs[kq * 4 + 0][nl] = v.x;
      Bs[kq * 4 + 1][nl] = v.y;
      Bs[kq * 4 + 2][nl] = v.z;
      Bs[kq * 4 + 3][nl] = v.w;
    }
    __syncthreads();
    #pragma unroll
    for (int kk = 0; kk < 64; ++kk) {
      float4 a  = *reinterpret_cast<const float4*>(&As[kk][m0]);
      float4 b0 = *reinterpret_cast<const float4*>(&Bs[kk][n0]);
      float4 b1 = *reinterpret_cast<const float4*>(&Bs[kk][n0 + 4]);
      float av[4] = {a.x, a.y, a.z, a.w};
      float bv[8] = {b0.x, b0.y, b0.z, b0.w, b1.x, b1.y, b1.z, b1.w};
      #pragma unroll
      for (int i = 0; i < 4; ++i)
        #pragma unroll
        for (int j = 0; j < 8; ++j) acc[i][j] += av[i] * bv[j];
    }
  }
  #pragma unroll
  for (int i = 0; i < 4; ++i) {
    int b = m0 + i;
    float4 o0 = make_float4(acc[i][0] + biasS[n0 + 0], acc[i][1] + biasS[n0 + 1],
                            acc[i][2] + biasS[n0 + 2], acc[i][3] + biasS[n0 + 3]);
    float4 o1 = make_float4(acc[i][4] + biasS[n0 + 4], acc[i][5] + biasS[n0 + 5],
                            acc[i][6] + biasS[n0 + 6], acc[i][7] + biasS[n0 + 7]);
    float* p = ht + (size_t)b * 65536 + nbase + n0;
    *reinterpret_cast<float4*>(p)     = o0;
    *reinterpret_cast<float4*>(p + 4) = o1;
  }
}

// ---------------- fg (fused): compute fg, emit hi/lo bf16 (K-concat) + row norms ----------------
__global__ __launch_bounds__(256) void k_fg2(const int* __restrict__ roles,
                                             const float* __restrict__ role_emb,
                                             const float* __restrict__ ht,
                                             unsigned short* __restrict__ fg2,
                                             float* __restrict__ fgn) {
  __shared__ float As[64][40];
  __shared__ float Bs[64][264];
  __shared__ int sidx[32];
  const int tid = threadIdx.x;
  const int b = blockIdx.x >> 2;
  const int sbase = (blockIdx.x & 3) * 32;
  const int tm = tid >> 5, tn = tid & 31;
  const int m0 = tm * 4, n0 = tn * 8;
  if (tid < 32) sidx[tid] = roles[b * 128 + sbase + tid];

  float acc[4][8];
  #pragma unroll
  for (int i = 0; i < 4; ++i)
    #pragma unroll
    for (int j = 0; j < 8; ++j) acc[i][j] = 0.f;

  for (int kt = 0; kt < 4; ++kt) {
    __syncthreads();
    #pragma unroll
    for (int i = 0; i < 2; ++i) {
      int q = tid + i * 256;
      int s = q >> 4, rq = q & 15;
      float4 v = *reinterpret_cast<const float4*>(role_emb + (size_t)sidx[s] * 256 + kt * 64 + rq * 4);
      As[rq * 4 + 0][s] = v.x;
      As[rq * 4 + 1][s] = v.y;
      As[rq * 4 + 2][s] = v.z;
      As[rq * 4 + 3][s] = v.w;
    }
    #pragma unroll
    for (int i = 0; i < 16; ++i) {
      int q = tid + i * 256;
      int rr = q >> 6, fq = q & 63;
      float4 v = *reinterpret_cast<const float4*>(ht + (size_t)b * 65536 + (size_t)(kt * 64 + rr) * 256 + fq * 4);
      *reinterpret_cast<float4*>(&Bs[rr][fq * 4]) = v;
    }
    __syncthreads();
    #pragma unroll
    for (int kk = 0; kk < 64; ++kk) {
      float4 a  = *reinterpret_cast<const float4*>(&As[kk][m0]);
      float4 b0 = *reinterpret_cast<const float4*>(&Bs[kk][n0]);
      float4 b1 = *reinterpret_cast<const float4*>(&Bs[kk][n0 + 4]);
      float av[4] = {a.x, a.y, a.z, a.w};
      float bv[8] = {b0.x, b0.y, b0.z, b0.w, b1.x, b1.y, b1.z, b1.w};
      #pragma unroll
      for (int i = 0; i < 4; ++i)
        #pragma unroll
        for (int j = 0; j < 8; ++j) acc[i][j] += av[i] * bv[j];
    }
  }
  #pragma unroll
  for (int i = 0; i < 4; ++i) {
    const int grow = b * 128 + sbase + m0 + i;
    float nrm = 0.f;
    unsigned int hp[4], lp[4];
    #pragma unroll
    for (int j = 0; j < 8; j += 2) {
      float x0 = acc[i][j], x1 = acc[i][j + 1];
      nrm += x0 * x0 + x1 * x1;
      unsigned short h0 = f2bf(x0), h1 = f2bf(x1);
      unsigned short l0 = f2bf(x0 - bf2f(h0)), l1 = f2bf(x1 - bf2f(h1));
      hp[j >> 1] = h0 | ((unsigned)h1 << 16);
      lp[j >> 1] = l0 | ((unsigned)l1 << 16);
    }
    *reinterpret_cast<uint4*>(fg2 + (size_t)grow * 512 + n0)       = make_uint4(hp[0], hp[1], hp[2], hp[3]);
    *reinterpret_cast<uint4*>(fg2 + (size_t)grow * 512 + 256 + n0) = make_uint4(lp[0], lp[1], lp[2], lp[3]);
    #pragma unroll
    for (int msk = 1; msk <= 16; msk <<= 1) nrm += __shfl_xor(nrm, msk, 64);
    if (tn == 0) fgn[grow] = nrm;
  }
}

// ---------------- MFMA distance GEMM (bf16 hi/lo, 3 cross-terms, K_eff=768) ----------------
// grid 64*79; 128x128 tile, BK=64, 4 waves (2x2), 16x16x32 bf16 MFMA.
// LDS linear (global_load_lds), XOR chunk swizzle applied on the GLOBAL source address;
// ds_read uses the matching XOR -> even spread over all 8 LDS bank groups.
__global__ __launch_bounds__(256, 2) void k_dist(const unsigned short* __restrict__ fg2,
                                                 const unsigned short* __restrict__ fl2,
                                                 const float* __restrict__ fgn,
                                                 const float* __restrict__ fln,
                                                 float* __restrict__ out,
                                                 float* __restrict__ parts) {
  __shared__ __align__(16) char lds[2][2][16384];   // [buf][A|B] 128 rows x 64 bf16
  __shared__ float rn2s[128], cn2s[128];
  const int tid = threadIdx.x;
  const int w = tid >> 6, l = tid & 63;
  const int g = l >> 4, lr = l & 15;
  const int swz = (blockIdx.x & 7) * 632 + (blockIdx.x >> 3);   // 5056 = 8*632, bijective
  const int mt = swz & 63, nt = swz >> 6;
  const int rbase = mt << 7, nbase = nt << 7;
  const int wm = (w >> 1) << 6, wn = (w & 1) << 6;

  if (tid < 128) { rn2s[tid] = fgn[rbase + tid]; cn2s[tid] = fln[nbase + tid]; }

  // per-lane source element offsets for the 4 staging instructions (A and B)
  int baseA[4], baseB[4];
  #pragma unroll
  for (int t = 0; t < 4; ++t) {
    int p = (w << 8) + (t << 6) + l;      // chunk index in tile
    int row = p >> 3, c = p & 7;
    int sw = ((c ^ (row & 7)) << 3);
    baseA[t] = (rbase + row) * 512 + sw;
    baseB[t] = (nbase + row) * 512 + sw;
  }
  // per-lane ds_read byte offsets (k-slice 0); slice 1 = ^64
  int offA[4], offB[4];
  #pragma unroll
  for (int i = 0; i < 4; ++i) {
    int ra = wm + (i << 4) + lr;
    offA[i] = ra * 128 + ((g ^ (ra & 7)) << 4);
    int rb = wn + (i << 4) + lr;
    offB[i] = rb * 128 + ((g ^ (rb & 7)) << 4);
  }

  f4v acc[4][4];
  #pragma unroll
  for (int i = 0; i < 4; ++i)
    #pragma unroll
    for (int j = 0; j < 4; ++j) acc[i][j] = (f4v)0.f;

  auto stage = [&](int buf, int kt2) {
    const int kA = ((kt2 & 3) << 6) + ((kt2 & 4) ? 256 : 0);  // kt 4-7: lo(A)
    const int kB = ((kt2 & 3) << 6) + ((kt2 & 8) ? 256 : 0);  // kt 8-11: lo(B)
    #pragma unroll
    for (int t = 0; t < 4; ++t) {
      GLD16(fg2 + (baseA[t] + kA), &lds[buf][0][(w << 12) + (t << 10)]);
      GLD16(fl2 + (baseB[t] + kB), &lds[buf][1][(w << 12) + (t << 10)]);
    }
  };

  stage(0, 0);
  __syncthreads();

  for (int kt = 0; kt < 12; ++kt) {
    const int cur = kt & 1;
    if (kt < 11) stage(cur ^ 1, kt + 1);
    const char* A = lds[cur][0];
    const char* B = lds[cur][1];
    #pragma unroll
    for (int s = 0; s < 2; ++s) {
      s8v av[4], bv[4];
      #pragma unroll
      for (int i = 0; i < 4; ++i) {
        av[i] = *reinterpret_cast<const s8v*>(A + (offA[i] ^ (s << 6)));
        bv[i] = *reinterpret_cast<const s8v*>(B + (offB[i] ^ (s << 6)));
      }
      #pragma unroll
      for (int i = 0; i < 4; ++i)
        #pragma unroll
        for (int j = 0; j < 4; ++j)
          acc[i][j] = __builtin_amdgcn_mfma_f32_16x16x32_bf16(av[i], bv[j], acc[i][j], 0, 0, 0);
    }
    __syncthreads();
  }

  // epilogue: d = sqrt(rn2 - 2*dot + cn2), store, online stats per row over 128 cols
  float cn[4];
  #pragma unroll
  for (int j = 0; j < 4; ++j) cn[j] = cn2s[wn + (j << 4) + lr];
  float* pScr = reinterpret_cast<float*>(&lds[0][0][0]);   // 128 rows x 2 wavecols x 4

  #pragma unroll
  for (int i = 0; i < 4; ++i) {
    #pragma unroll
    for (int r = 0; r < 4; ++r) {
      const int rowloc = wm + (i << 4) + (g << 2) + r;
      const float r2 = rn2s[rowloc];
      const size_t orow = (size_t)(rbase + rowloc) * NF + nbase;
      float dv[4]; int cols[4];
      #pragma unroll
      for (int j = 0; j < 4; ++j) {
        const int cloc = wn + (j << 4) + lr;
        const int gcol = nbase + cloc;
        float d2 = r2 - 2.0f * acc[i][j][r] + cn[j];
        float d = sqrtf(fmaxf(d2, 0.f));
        cols[j] = gcol;
        if (gcol < NF) { out[orow + cloc] = d; dv[j] = d; }
        else dv[j] = 1e30f;
      }
      float bd = dv[0]; int bn = cols[0];
      #pragma unroll
      for (int j = 1; j < 4; ++j)
        if (dv[j] < bd) { bd = dv[j]; bn = cols[j]; }
      #pragma unroll
      for (int msk = 1; msk <= 8; msk <<= 1) {
        float od = __shfl_xor(bd, msk, 64);
        int   on = __shfl_xor(bn, msk, 64);
        if (od < bd || (od == bd && on < bn)) { bd = od; bn = on; }
      }
      float s = 0.f;
      #pragma unroll
      for (int j = 0; j < 4; ++j) s += __expf(bd - dv[j]);
      #pragma unroll
      for (int msk = 1; msk <= 8; msk <<= 1) s += __shfl_xor(s, msk, 64);
      if (lr == 0) {
        float* q = pScr + (rowloc << 3) + ((w & 1) << 2);
        q[0] = bd; q[1] = s; q[2] = (float)bn;
      }
    }
  }
  __syncthreads();
  if (tid < 128) {
    const float* q = pScr + (tid << 3);
    float m0 = q[0], s0 = q[1]; float n0f = q[2];
    float m1 = q[4], s1 = q[5]; float n1f = q[6];
    float m = fminf(m0, m1);
    float S = s0 * __expf(m - m0) + s1 * __expf(m - m1);
    float bd, bn;
    if (m1 < m0 || (m1 == m0 && n1f < n0f)) { bd = m1; bn = n1f; }
    else                                    { bd = m0; bn = n0f; }
    float* p = parts + (((size_t)(rbase + tid)) * 80 + nt) * 4;
    p[0] = m; p[1] = S; p[2] = bd; p[3] = bn;
  }
}

// ---------------- combine 79 strips -> LSE + preds, then logp = -d - LSE ----------------
__global__ __launch_bounds__(256) void k_final(const float* __restrict__ parts,
                                               float* __restrict__ out) {
  const int row = blockIdx.x;
  __shared__ float sm[80][4];
  __shared__ float shL;
  const int t = threadIdx.x;
  if (t < 79)
    *reinterpret_cast<float4*>(sm[t]) =
        *reinterpret_cast<const float4*>(parts + ((size_t)row * 80 + t) * 4);
  __syncthreads();
  if (t == 0) {
    float m = FLT_MAX;
    for (int s = 0; s < 79; ++s) m = fminf(m, sm[s][0]);
    float S = 0.f;
    for (int s = 0; s < 79; ++s) S += sm[s][1] * __expf(m - sm[s][0]);
    float bd = FLT_MAX, bn = 0.f;
    for (int s = 0; s < 79; ++s) {
      float dd = sm[s][2], nn = sm[s][3];
      if (dd < bd || (dd == bd && nn < bn)) { bd = dd; bn = nn; }
    }
    shL = logf(S) - m;
    out[(size_t)ROWS * NF + row] = bn;        // preds
  }
  __syncthreads();
  const float L = shL;
  float4* prow = reinterpret_cast<float4*>(out + (size_t)row * NF);
  for (int c = t; c < 2500; c += 256) {
    float4 v = prow[c];
    v.x = -v.x - L; v.y = -v.y - L; v.z = -v.z - L; v.w = -v.w - L;
    prow[c] = v;
  }
}

extern "C" void kernel_launch(void* const* d_in, const int* in_sizes, int n_in,
                              void* d_out, int out_size, void* d_ws, size_t ws_size,
                              hipStream_t stream) {
  const int*   roles   = (const int*)d_in[0];
  const float* hidden  = (const float*)d_in[1];
  const float* filler  = (const float*)d_in[2];
  const float* roleemb = (const float*)d_in[3];
  const float* W       = (const float*)d_in[4];
  const float* bias    = (const float*)d_in[5];
  float* out = (float*)d_out;

  float* ws = (float*)d_ws;
  float*          ht    = ws;                                        // 4,194,304 f32
  unsigned short* fg2   = (unsigned short*)(ws + 4194304);           // 8192 x 512 bf16
  unsigned short* fl2   = (unsigned short*)(ws + 4194304 + 2097152); // 10112 x 512 bf16
  float*          fgn   = ws + 4194304 + 2097152 + 2589696;          // 8192
  float*          fln   = fgn + 8192;                                // 10112 (pad=1e30)
  float*          parts = fln + 10112;                               // 8192 x 80 x 4

  k_cvt_filler<<<2528, 256, 0, stream>>>(filler, fl2, fln);
  k_gemm1<<<512, 256, 0, stream>>>(hidden, W, bias, ht);
  k_fg2<<<256, 256, 0, stream>>>(roles, roleemb, ht, fg2, fgn);
  k_dist<<<5056, 256, 0, stream>>>(fg2, fl2, fgn, fln, out, parts);
  k_final<<<8192, 256, 0, stream>>>(parts, out);
}

// Round 4
// 635.715 us; speedup vs baseline: 1.8987x; 1.1567x over previous
//
#include <hip/hip_runtime.h>
#include <hip/hip_bf16.h>
#include <float.h>
#include <math.h>

#define ROWS 8192     // B*S
#define NF   10000    // n_fillers
#define NPAD 10240    // 40 * 256

typedef short s8v __attribute__((ext_vector_type(8)));
typedef float f4v __attribute__((ext_vector_type(4)));

#define GLD16(g, l) __builtin_amdgcn_global_load_lds((const __attribute__((address_space(1))) void*)(g), (__attribute__((address_space(3))) void*)(l), 16, 0, 0)

__device__ inline unsigned short f2bf(float x) {
  __hip_bfloat16 h = __float2bfloat16(x);
  return __builtin_bit_cast(unsigned short, h);
}
__device__ inline float bf2f(unsigned short u) {
  __hip_bfloat16 h = __builtin_bit_cast(__hip_bfloat16, u);
  return __bfloat162float(h);
}

// ---------------- filler: row norms + hi/lo bf16 conversion (rows padded to NPAD) ----------------
__global__ __launch_bounds__(256) void k_cvt_filler(const float* __restrict__ filler,
                                                    unsigned short* __restrict__ fl2,
                                                    float* __restrict__ fln) {
  int row = blockIdx.x * 4 + (threadIdx.x >> 6);
  int lane = threadIdx.x & 63;
  if (row >= NPAD) return;
  if (row < NF) {
    float4 v = reinterpret_cast<const float4*>(filler + (size_t)row * 256)[lane];
    float s = v.x * v.x + v.y * v.y + v.z * v.z + v.w * v.w;
    #pragma unroll
    for (int off = 32; off >= 1; off >>= 1) s += __shfl_xor(s, off, 64);
    if (lane == 0) fln[row] = s;
    float xs[4] = {v.x, v.y, v.z, v.w};
    unsigned short h[4], lo[4];
    #pragma unroll
    for (int j = 0; j < 4; ++j) { h[j] = f2bf(xs[j]); lo[j] = f2bf(xs[j] - bf2f(h[j])); }
    uint2 hh = make_uint2(h[0] | ((unsigned)h[1] << 16), h[2] | ((unsigned)h[3] << 16));
    uint2 ll = make_uint2(lo[0] | ((unsigned)lo[1] << 16), lo[2] | ((unsigned)lo[3] << 16));
    *reinterpret_cast<uint2*>(fl2 + (size_t)row * 512 + lane * 4) = hh;
    *reinterpret_cast<uint2*>(fl2 + (size_t)row * 512 + 256 + lane * 4) = ll;
  } else {
    *reinterpret_cast<uint2*>(fl2 + (size_t)row * 512 + lane * 4) = make_uint2(0, 0);
    *reinterpret_cast<uint2*>(fl2 + (size_t)row * 512 + 256 + lane * 4) = make_uint2(0, 0);
    if (lane == 0) fln[row] = 1e30f;
  }
}

// ---------------- GEMM1: ht[b, r*256+f] = sum_k hidden[b,k]*W[f*256+r,k] + bias[f*256+r]
__global__ __launch_bounds__(256) void k_gemm1(const float* __restrict__ hidden,
                                               const float* __restrict__ W,
                                               const float* __restrict__ bias,
                                               float* __restrict__ ht) {
  __shared__ float As[64][68];
  __shared__ float Bs[64][136];
  __shared__ float biasS[128];
  const int tid = threadIdx.x;
  const int nbase = blockIdx.x * 128;
  const int r = nbase >> 8;
  const int f0 = nbase & 255;
  const int tm = tid >> 4, tn = tid & 15;
  const int m0 = tm * 4, n0 = tn * 8;

  if (tid < 128) biasS[tid] = bias[(size_t)(f0 + tid) * 256 + r];

  float acc[4][8];
  #pragma unroll
  for (int i = 0; i < 4; ++i)
    #pragma unroll
    for (int j = 0; j < 8; ++j) acc[i][j] = 0.f;

  for (int kt = 0; kt < 16; ++kt) {
    __syncthreads();
    #pragma unroll
    for (int i = 0; i < 4; ++i) {
      int q = tid + i * 256;
      int b = q >> 4, kq = q & 15;
      float4 v = *reinterpret_cast<const float4*>(hidden + (size_t)b * 1024 + kt * 64 + kq * 4);
      As[kq * 4 + 0][b] = v.x;
      As[kq * 4 + 1][b] = v.y;
      As[kq * 4 + 2][b] = v.z;
      As[kq * 4 + 3][b] = v.w;
    }
    #pragma unroll
    for (int i = 0; i < 8; ++i) {
      int q = tid + i * 256;
      int nl = q >> 4, kq = q & 15;
      size_t wrow = (size_t)(f0 + nl) * 256 + r;
      float4 v = *reinterpret_cast<const float4*>(W + wrow * 1024 + kt * 64 + kq * 4);
      Bs[kq * 4 + 0][nl] = v.x;
      Bs[kq * 4 + 1][nl] = v.y;
      Bs[kq * 4 + 2][nl] = v.z;
      Bs[kq * 4 + 3][nl] = v.w;
    }
    __syncthreads();
    #pragma unroll
    for (int kk = 0; kk < 64; ++kk) {
      float4 a  = *reinterpret_cast<const float4*>(&As[kk][m0]);
      float4 b0 = *reinterpret_cast<const float4*>(&Bs[kk][n0]);
      float4 b1 = *reinterpret_cast<const float4*>(&Bs[kk][n0 + 4]);
      float av[4] = {a.x, a.y, a.z, a.w};
      float bv[8] = {b0.x, b0.y, b0.z, b0.w, b1.x, b1.y, b1.z, b1.w};
      #pragma unroll
      for (int i = 0; i < 4; ++i)
        #pragma unroll
        for (int j = 0; j < 8; ++j) acc[i][j] += av[i] * bv[j];
    }
  }
  #pragma unroll
  for (int i = 0; i < 4; ++i) {
    int b = m0 + i;
    float4 o0 = make_float4(acc[i][0] + biasS[n0 + 0], acc[i][1] + biasS[n0 + 1],
                            acc[i][2] + biasS[n0 + 2], acc[i][3] + biasS[n0 + 3]);
    float4 o1 = make_float4(acc[i][4] + biasS[n0 + 4], acc[i][5] + biasS[n0 + 5],
                            acc[i][6] + biasS[n0 + 6], acc[i][7] + biasS[n0 + 7]);
    float* p = ht + (size_t)b * 65536 + nbase + n0;
    *reinterpret_cast<float4*>(p)     = o0;
    *reinterpret_cast<float4*>(p + 4) = o1;
  }
}

// ---------------- fg (fused): compute fg, emit hi/lo bf16 (K-concat) + row norms ----------------
__global__ __launch_bounds__(256) void k_fg2(const int* __restrict__ roles,
                                             const float* __restrict__ role_emb,
                                             const float* __restrict__ ht,
                                             unsigned short* __restrict__ fg2,
                                             float* __restrict__ fgn) {
  __shared__ float As[64][40];
  __shared__ float Bs[64][264];
  __shared__ int sidx[32];
  const int tid = threadIdx.x;
  const int b = blockIdx.x >> 2;
  const int sbase = (blockIdx.x & 3) * 32;
  const int tm = tid >> 5, tn = tid & 31;
  const int m0 = tm * 4, n0 = tn * 8;
  if (tid < 32) sidx[tid] = roles[b * 128 + sbase + tid];

  float acc[4][8];
  #pragma unroll
  for (int i = 0; i < 4; ++i)
    #pragma unroll
    for (int j = 0; j < 8; ++j) acc[i][j] = 0.f;

  for (int kt = 0; kt < 4; ++kt) {
    __syncthreads();
    #pragma unroll
    for (int i = 0; i < 2; ++i) {
      int q = tid + i * 256;
      int s = q >> 4, rq = q & 15;
      float4 v = *reinterpret_cast<const float4*>(role_emb + (size_t)sidx[s] * 256 + kt * 64 + rq * 4);
      As[rq * 4 + 0][s] = v.x;
      As[rq * 4 + 1][s] = v.y;
      As[rq * 4 + 2][s] = v.z;
      As[rq * 4 + 3][s] = v.w;
    }
    #pragma unroll
    for (int i = 0; i < 16; ++i) {
      int q = tid + i * 256;
      int rr = q >> 6, fq = q & 63;
      float4 v = *reinterpret_cast<const float4*>(ht + (size_t)b * 65536 + (size_t)(kt * 64 + rr) * 256 + fq * 4);
      *reinterpret_cast<float4*>(&Bs[rr][fq * 4]) = v;
    }
    __syncthreads();
    #pragma unroll
    for (int kk = 0; kk < 64; ++kk) {
      float4 a  = *reinterpret_cast<const float4*>(&As[kk][m0]);
      float4 b0 = *reinterpret_cast<const float4*>(&Bs[kk][n0]);
      float4 b1 = *reinterpret_cast<const float4*>(&Bs[kk][n0 + 4]);
      float av[4] = {a.x, a.y, a.z, a.w};
      float bv[8] = {b0.x, b0.y, b0.z, b0.w, b1.x, b1.y, b1.z, b1.w};
      #pragma unroll
      for (int i = 0; i < 4; ++i)
        #pragma unroll
        for (int j = 0; j < 8; ++j) acc[i][j] += av[i] * bv[j];
    }
  }
  #pragma unroll
  for (int i = 0; i < 4; ++i) {
    const int grow = b * 128 + sbase + m0 + i;
    float nrm = 0.f;
    unsigned int hp[4], lp[4];
    #pragma unroll
    for (int j = 0; j < 8; j += 2) {
      float x0 = acc[i][j], x1 = acc[i][j + 1];
      nrm += x0 * x0 + x1 * x1;
      unsigned short h0 = f2bf(x0), h1 = f2bf(x1);
      unsigned short l0 = f2bf(x0 - bf2f(h0)), l1 = f2bf(x1 - bf2f(h1));
      hp[j >> 1] = h0 | ((unsigned)h1 << 16);
      lp[j >> 1] = l0 | ((unsigned)l1 << 16);
    }
    *reinterpret_cast<uint4*>(fg2 + (size_t)grow * 512 + n0)       = make_uint4(hp[0], hp[1], hp[2], hp[3]);
    *reinterpret_cast<uint4*>(fg2 + (size_t)grow * 512 + 256 + n0) = make_uint4(lp[0], lp[1], lp[2], lp[3]);
    #pragma unroll
    for (int msk = 1; msk <= 16; msk <<= 1) nrm += __shfl_xor(nrm, msk, 64);
    if (tn == 0) fgn[grow] = nrm;
  }
}

// ---------------- MFMA distance GEMM: 256x256 tile, 8 waves, 8-phase-style schedule ----------------
// K_eff = 768 = 12 kt of 64 = 24 half-tiles of 32. LDS: 4 regions (A 16KB | B 16KB).
// 3-deep prefetch, counted vmcnt(8); per half-tile 2 phases of 16 MFMA.
__global__ __launch_bounds__(512, 2) void k_dist(const unsigned short* __restrict__ fg2,
                                                 const unsigned short* __restrict__ fl2,
                                                 const float* __restrict__ fgn,
                                                 const float* __restrict__ fln,
                                                 float* __restrict__ out,
                                                 float* __restrict__ parts) {
  __shared__ __align__(16) char lds[4][32768];
  __shared__ float rn2s[256], cn2s[256];
  const int tid = threadIdx.x;
  const int w = tid >> 6, l = tid & 63;
  const int g = l >> 4, lr = l & 15;
  // grid 1280 = 8 XCD chunks of 160
  const int swz = (blockIdx.x & 7) * 160 + (blockIdx.x >> 3);
  const int mt = swz & 31, nt = swz >> 5;            // 32 x 40
  const int rbase = mt << 8, nbase = nt << 8;
  const int wm = (w >> 2) << 7;                      // 0 / 128
  const int wn = (w & 3) << 6;                       // 0,64,128,192

  if (tid < 256) { rn2s[tid] = fgn[rbase + tid]; cn2s[tid] = fln[nbase + tid]; }

  // staging source element-offsets (swizzled on the GLOBAL side; LDS stays linear)
  int baseA[2], baseB[2];
  #pragma unroll
  for (int t = 0; t < 2; ++t) {
    int p = (w * 2 + t) * 64 + l;       // chunk id 0..1023 (16B chunks of a 256x32 tile)
    int row = p >> 2, c = p & 3;
    int sw = (c ^ (row & 3)) << 3;
    baseA[t] = (rbase + row) * 512 + sw;
    baseB[t] = (nbase + row) * 512 + sw;
  }
  const int dstOff = w * 2048;          // per-wave LDS dest (2 x 1024B per half)

  // ds_read byte offsets within a region (A at 0, B at 16384); row stride 64B, chunk XOR
  int offA[8], offB[4];
  #pragma unroll
  for (int i = 0; i < 8; ++i) { int r = wm + i * 16 + lr; offA[i] = r * 64 + ((g ^ (r & 3)) << 4); }
  #pragma unroll
  for (int j = 0; j < 4; ++j) { int r = wn + j * 16 + lr; offB[j] = 16384 + r * 64 + ((g ^ (r & 3)) << 4); }

  f4v acc[8][4];
  #pragma unroll
  for (int i = 0; i < 8; ++i)
    #pragma unroll
    for (int j = 0; j < 4; ++j) acc[i][j] = (f4v)0.f;

  // k offsets for half-tile h: kt = h>>1 (0..11), slice = h&1
  auto kAof = [](int h) { int kt = h >> 1; return ((kt & 3) << 6) + ((kt & 4) ? 256 : 0) + ((h & 1) << 5); };
  auto kBof = [](int h) { int kt = h >> 1; return ((kt & 3) << 6) + ((kt >= 8) ? 256 : 0) + ((h & 1) << 5); };

  auto stageA = [&](int dst, int src) {
    const int kA = kAof(src);
    char* base = &lds[dst][0] + dstOff;
    GLD16(fg2 + (baseA[0] + kA), base);
    GLD16(fg2 + (baseA[1] + kA), base + 1024);
  };
  auto stageB = [&](int dst, int src) {
    const int kB = kBof(src);
    char* base = &lds[dst][16384] + dstOff;
    GLD16(fl2 + (baseB[0] + kB), base);
    GLD16(fl2 + (baseB[1] + kB), base + 1024);
  };

  // prologue: stage half-tiles 0,1,2 (12 vm instrs); wait for tile 0 (vmcnt 8 = tiles 1,2 in flight)
  #pragma unroll
  for (int hh = 0; hh < 3; ++hh) { stageA(hh, hh); stageB(hh, hh); }
  asm volatile("s_waitcnt vmcnt(8)" ::: "memory");
  __builtin_amdgcn_s_barrier();

  s8v va[4], vb[4];
  for (int h = 0; h < 24; ++h) {
    const char* A = &lds[h & 3][0];
    const int dst = (h + 3) & 3;
    const int src = (h + 3 <= 23) ? (h + 3) : 23;   // dummy re-stage keeps vmcnt literal valid

    // ---- phase A: C rows wm..wm+63 ----
    #pragma unroll
    for (int i = 0; i < 4; ++i) va[i] = *reinterpret_cast<const s8v*>(A + offA[i]);
    #pragma unroll
    for (int j = 0; j < 4; ++j) vb[j] = *reinterpret_cast<const s8v*>(A + offB[j]);
    stageA(dst, src);
    __builtin_amdgcn_s_barrier();
    asm volatile("s_waitcnt lgkmcnt(0)" ::: "memory");
    __builtin_amdgcn_sched_barrier(0);
    __builtin_amdgcn_s_setprio(1);
    #pragma unroll
    for (int i = 0; i < 4; ++i)
      #pragma unroll
      for (int j = 0; j < 4; ++j)
        acc[i][j] = __builtin_amdgcn_mfma_f32_16x16x32_bf16(va[i], vb[j], acc[i][j], 0, 0, 0);
    __builtin_amdgcn_s_setprio(0);
    __builtin_amdgcn_s_barrier();

    // ---- phase B: C rows wm+64..wm+127 (reuse vb) ----
    #pragma unroll
    for (int i = 0; i < 4; ++i) va[i] = *reinterpret_cast<const s8v*>(A + offA[4 + i]);
    stageB(dst, src);
    asm volatile("s_waitcnt vmcnt(8)" ::: "memory");   // half-tile h+1 fully landed (per-wave)
    __builtin_amdgcn_s_barrier();
    asm volatile("s_waitcnt lgkmcnt(0)" ::: "memory");
    __builtin_amdgcn_sched_barrier(0);
    __builtin_amdgcn_s_setprio(1);
    #pragma unroll
    for (int i = 0; i < 4; ++i)
      #pragma unroll
      for (int j = 0; j < 4; ++j)
        acc[4 + i][j] = __builtin_amdgcn_mfma_f32_16x16x32_bf16(va[i], vb[j], acc[4 + i][j], 0, 0, 0);
    __builtin_amdgcn_s_setprio(0);
    __builtin_amdgcn_s_barrier();
  }

  // drain all outstanding staging before reusing LDS as scratch
  asm volatile("s_waitcnt vmcnt(0)" ::: "memory");
  __builtin_amdgcn_s_barrier();

  // ---- epilogue: dist, store, per-row stats over this block's 256 cols ----
  float cn[4];
  #pragma unroll
  for (int j = 0; j < 4; ++j) cn[j] = cn2s[wn + (j << 4) + lr];
  float* scr = reinterpret_cast<float*>(&lds[0][0]);   // 256 rows x 4 wavecols x 4 floats = 16KB

  #pragma unroll
  for (int i = 0; i < 8; ++i) {
    #pragma unroll
    for (int r = 0; r < 4; ++r) {
      const int rowloc = wm + (i << 4) + (g << 2) + r;
      const float r2 = rn2s[rowloc];
      const size_t orow = (size_t)(rbase + rowloc) * NF + nbase;
      float dv[4];
      #pragma unroll
      for (int j = 0; j < 4; ++j) {
        const int cloc = wn + (j << 4) + lr;
        float d2 = r2 - 2.0f * acc[i][j][r] + cn[j];
        float d = sqrtf(fmaxf(d2, 0.f));
        dv[j] = d;
        if (nbase + cloc < NF) out[orow + cloc] = d;
      }
      float bd = dv[0]; int bn = nbase + wn + lr;
      #pragma unroll
      for (int j = 1; j < 4; ++j) {
        int col = nbase + wn + (j << 4) + lr;
        if (dv[j] < bd) { bd = dv[j]; bn = col; }
      }
      #pragma unroll
      for (int msk = 1; msk <= 8; msk <<= 1) {
        float od = __shfl_xor(bd, msk, 64);
        int   on = __shfl_xor(bn, msk, 64);
        if (od < bd || (od == bd && on < bn)) { bd = od; bn = on; }
      }
      float s = 0.f;
      #pragma unroll
      for (int j = 0; j < 4; ++j) s += __expf(bd - dv[j]);
      #pragma unroll
      for (int msk = 1; msk <= 8; msk <<= 1) s += __shfl_xor(s, msk, 64);
      if (lr == 0) {
        float* q = scr + (rowloc << 4) + ((w & 3) << 2);
        q[0] = bd; q[1] = s; q[2] = (float)bn;
      }
    }
  }
  __syncthreads();
  if (tid < 256) {
    const float* q = scr + (tid << 4);
    float M = q[0], bn = q[2];
    #pragma unroll
    for (int c = 1; c < 4; ++c)
      if (q[c * 4] < M) { M = q[c * 4]; bn = q[c * 4 + 2]; }
    float S = 0.f;
    #pragma unroll
    for (int c = 0; c < 4; ++c) S += q[c * 4 + 1] * __expf(M - q[c * 4]);
    float* p = parts + (((size_t)(rbase + tid)) * 40 + nt) * 4;
    p[0] = M; p[1] = S; p[2] = M; p[3] = bn;
  }
}

// ---------------- combine 40 strips -> LSE + preds, then logp = -d - LSE ----------------
__global__ __launch_bounds__(256) void k_final(const float* __restrict__ parts,
                                               float* __restrict__ out) {
  const int row = blockIdx.x;
  __shared__ float sm[40][4];
  __shared__ float shL;
  const int t = threadIdx.x;
  if (t < 40)
    *reinterpret_cast<float4*>(sm[t]) =
        *reinterpret_cast<const float4*>(parts + ((size_t)row * 40 + t) * 4);
  __syncthreads();
  if (t == 0) {
    float m = FLT_MAX;
    for (int s = 0; s < 40; ++s) m = fminf(m, sm[s][0]);
    float S = 0.f;
    for (int s = 0; s < 40; ++s) S += sm[s][1] * __expf(m - sm[s][0]);
    float bd = FLT_MAX, bn = 0.f;
    for (int s = 0; s < 40; ++s) {
      float dd = sm[s][2], nn = sm[s][3];
      if (dd < bd || (dd == bd && nn < bn)) { bd = dd; bn = nn; }
    }
    shL = logf(S) - m;
    out[(size_t)ROWS * NF + row] = bn;        // preds
  }
  __syncthreads();
  const float L = shL;
  float4* prow = reinterpret_cast<float4*>(out + (size_t)row * NF);
  for (int c = t; c < 2500; c += 256) {
    float4 v = prow[c];
    v.x = -v.x - L; v.y = -v.y - L; v.z = -v.z - L; v.w = -v.w - L;
    prow[c] = v;
  }
}

extern "C" void kernel_launch(void* const* d_in, const int* in_sizes, int n_in,
                              void* d_out, int out_size, void* d_ws, size_t ws_size,
                              hipStream_t stream) {
  const int*   roles   = (const int*)d_in[0];
  const float* hidden  = (const float*)d_in[1];
  const float* filler  = (const float*)d_in[2];
  const float* roleemb = (const float*)d_in[3];
  const float* W       = (const float*)d_in[4];
  const float* bias    = (const float*)d_in[5];
  float* out = (float*)d_out;

  float* ws = (float*)d_ws;
  float*          ht    = ws;                               // 4,194,304 f32
  unsigned short* fg2   = (unsigned short*)(ws + 4194304);  // 8192 x 512 bf16
  unsigned short* fl2   = (unsigned short*)(ws + 6291456);  // 10240 x 512 bf16
  float*          fgn   = ws + 8912896;                     // 8192
  float*          fln   = fgn + 8192;                       // 10240 (pad=1e30)
  float*          parts = fln + 10240;                      // 8192 x 40 x 4

  k_cvt_filler<<<2560, 256, 0, stream>>>(filler, fl2, fln);
  k_gemm1<<<512, 256, 0, stream>>>(hidden, W, bias, ht);
  k_fg2<<<256, 256, 0, stream>>>(roles, roleemb, ht, fg2, fgn);
  k_dist<<<1280, 512, 0, stream>>>(fg2, fl2, fgn, fln, out, parts);
  k_final<<<8192, 256, 0, stream>>>(parts, out);
}

// Round 6
// 590.383 us; speedup vs baseline: 2.0445x; 1.0768x over previous
//
#include <hip/hip_runtime.h>
#include <hip/hip_bf16.h>
#include <float.h>
#include <math.h>

#define ROWS 8192     // B*S
#define NF   10000    // n_fillers
#define NPAD 10240    // 40 * 256

typedef short s8v __attribute__((ext_vector_type(8)));
typedef float f4v __attribute__((ext_vector_type(4)));

#define GLD16(g, l) __builtin_amdgcn_global_load_lds((const __attribute__((address_space(1))) void*)(g), (__attribute__((address_space(3))) void*)(l), 16, 0, 0)

__device__ inline unsigned short f2bf(float x) {
  __hip_bfloat16 h = __float2bfloat16(x);
  return __builtin_bit_cast(unsigned short, h);
}
__device__ inline float bf2f(unsigned short u) {
  __hip_bfloat16 h = __builtin_bit_cast(__hip_bfloat16, u);
  return __bfloat162float(h);
}

// ---------------- filler: row norms + hi/lo bf16 conversion (rows padded to NPAD) ----------------
__global__ __launch_bounds__(256) void k_cvt_filler(const float* __restrict__ filler,
                                                    unsigned short* __restrict__ fl2,
                                                    float* __restrict__ fln) {
  int row = blockIdx.x * 4 + (threadIdx.x >> 6);
  int lane = threadIdx.x & 63;
  if (row >= NPAD) return;
  if (row < NF) {
    float4 v = reinterpret_cast<const float4*>(filler + (size_t)row * 256)[lane];
    float s = v.x * v.x + v.y * v.y + v.z * v.z + v.w * v.w;
    #pragma unroll
    for (int off = 32; off >= 1; off >>= 1) s += __shfl_xor(s, off, 64);
    if (lane == 0) fln[row] = s;
    float xs[4] = {v.x, v.y, v.z, v.w};
    unsigned short h[4], lo[4];
    #pragma unroll
    for (int j = 0; j < 4; ++j) { h[j] = f2bf(xs[j]); lo[j] = f2bf(xs[j] - bf2f(h[j])); }
    uint2 hh = make_uint2(h[0] | ((unsigned)h[1] << 16), h[2] | ((unsigned)h[3] << 16));
    uint2 ll = make_uint2(lo[0] | ((unsigned)lo[1] << 16), lo[2] | ((unsigned)lo[3] << 16));
    *reinterpret_cast<uint2*>(fl2 + (size_t)row * 512 + lane * 4) = hh;
    *reinterpret_cast<uint2*>(fl2 + (size_t)row * 512 + 256 + lane * 4) = ll;
  } else {
    *reinterpret_cast<uint2*>(fl2 + (size_t)row * 512 + lane * 4) = make_uint2(0, 0);
    *reinterpret_cast<uint2*>(fl2 + (size_t)row * 512 + 256 + lane * 4) = make_uint2(0, 0);
    if (lane == 0) fln[row] = 1e30f;
  }
}

// ---------------- GEMM1: ht[b, r*256+f] = sum_k hidden[b,k]*W[f*256+r,k] + bias[f*256+r]
__global__ __launch_bounds__(256) void k_gemm1(const float* __restrict__ hidden,
                                               const float* __restrict__ W,
                                               const float* __restrict__ bias,
                                               float* __restrict__ ht) {
  __shared__ float As[64][68];
  __shared__ float Bs[64][136];
  __shared__ float biasS[128];
  const int tid = threadIdx.x;
  const int nbase = blockIdx.x * 128;
  const int r = nbase >> 8;
  const int f0 = nbase & 255;
  const int tm = tid >> 4, tn = tid & 15;
  const int m0 = tm * 4, n0 = tn * 8;

  if (tid < 128) biasS[tid] = bias[(size_t)(f0 + tid) * 256 + r];

  float acc[4][8];
  #pragma unroll
  for (int i = 0; i < 4; ++i)
    #pragma unroll
    for (int j = 0; j < 8; ++j) acc[i][j] = 0.f;

  for (int kt = 0; kt < 16; ++kt) {
    __syncthreads();
    #pragma unroll
    for (int i = 0; i < 4; ++i) {
      int q = tid + i * 256;
      int b = q >> 4, kq = q & 15;
      float4 v = *reinterpret_cast<const float4*>(hidden + (size_t)b * 1024 + kt * 64 + kq * 4);
      As[kq * 4 + 0][b] = v.x;
      As[kq * 4 + 1][b] = v.y;
      As[kq * 4 + 2][b] = v.z;
      As[kq * 4 + 3][b] = v.w;
    }
    #pragma unroll
    for (int i = 0; i < 8; ++i) {
      int q = tid + i * 256;
      int nl = q >> 4, kq = q & 15;
      size_t wrow = (size_t)(f0 + nl) * 256 + r;
      float4 v = *reinterpret_cast<const float4*>(W + wrow * 1024 + kt * 64 + kq * 4);
      Bs[kq * 4 + 0][nl] = v.x;
      Bs[kq * 4 + 1][nl] = v.y;
      Bs[kq * 4 + 2][nl] = v.z;
      Bs[kq * 4 + 3][nl] = v.w;
    }
    __syncthreads();
    #pragma unroll
    for (int kk = 0; kk < 64; ++kk) {
      float4 a  = *reinterpret_cast<const float4*>(&As[kk][m0]);
      float4 b0 = *reinterpret_cast<const float4*>(&Bs[kk][n0]);
      float4 b1 = *reinterpret_cast<const float4*>(&Bs[kk][n0 + 4]);
      float av[4] = {a.x, a.y, a.z, a.w};
      float bv[8] = {b0.x, b0.y, b0.z, b0.w, b1.x, b1.y, b1.z, b1.w};
      #pragma unroll
      for (int i = 0; i < 4; ++i)
        #pragma unroll
        for (int j = 0; j < 8; ++j) acc[i][j] += av[i] * bv[j];
    }
  }
  #pragma unroll
  for (int i = 0; i < 4; ++i) {
    int b = m0 + i;
    float4 o0 = make_float4(acc[i][0] + biasS[n0 + 0], acc[i][1] + biasS[n0 + 1],
                            acc[i][2] + biasS[n0 + 2], acc[i][3] + biasS[n0 + 3]);
    float4 o1 = make_float4(acc[i][4] + biasS[n0 + 4], acc[i][5] + biasS[n0 + 5],
                            acc[i][6] + biasS[n0 + 6], acc[i][7] + biasS[n0 + 7]);
    float* p = ht + (size_t)b * 65536 + nbase + n0;
    *reinterpret_cast<float4*>(p)     = o0;
    *reinterpret_cast<float4*>(p + 4) = o1;
  }
}

// ---------------- fg (fused): compute fg, emit hi/lo bf16 (K-concat) + row norms ----------------
__global__ __launch_bounds__(256) void k_fg2(const int* __restrict__ roles,
                                             const float* __restrict__ role_emb,
                                             const float* __restrict__ ht,
                                             unsigned short* __restrict__ fg2,
                                             float* __restrict__ fgn) {
  __shared__ float As[64][40];
  __shared__ float Bs[64][264];
  __shared__ int sidx[32];
  const int tid = threadIdx.x;
  const int b = blockIdx.x >> 2;
  const int sbase = (blockIdx.x & 3) * 32;
  const int tm = tid >> 5, tn = tid & 31;
  const int m0 = tm * 4, n0 = tn * 8;
  if (tid < 32) sidx[tid] = roles[b * 128 + sbase + tid];

  float acc[4][8];
  #pragma unroll
  for (int i = 0; i < 4; ++i)
    #pragma unroll
    for (int j = 0; j < 8; ++j) acc[i][j] = 0.f;

  for (int kt = 0; kt < 4; ++kt) {
    __syncthreads();
    #pragma unroll
    for (int i = 0; i < 2; ++i) {
      int q = tid + i * 256;
      int s = q >> 4, rq = q & 15;
      float4 v = *reinterpret_cast<const float4*>(role_emb + (size_t)sidx[s] * 256 + kt * 64 + rq * 4);
      As[rq * 4 + 0][s] = v.x;
      As[rq * 4 + 1][s] = v.y;
      As[rq * 4 + 2][s] = v.z;
      As[rq * 4 + 3][s] = v.w;
    }
    #pragma unroll
    for (int i = 0; i < 16; ++i) {
      int q = tid + i * 256;
      int rr = q >> 6, fq = q & 63;
      float4 v = *reinterpret_cast<const float4*>(ht + (size_t)b * 65536 + (size_t)(kt * 64 + rr) * 256 + fq * 4);
      *reinterpret_cast<float4*>(&Bs[rr][fq * 4]) = v;
    }
    __syncthreads();
    #pragma unroll
    for (int kk = 0; kk < 64; ++kk) {
      float4 a  = *reinterpret_cast<const float4*>(&As[kk][m0]);
      float4 b0 = *reinterpret_cast<const float4*>(&Bs[kk][n0]);
      float4 b1 = *reinterpret_cast<const float4*>(&Bs[kk][n0 + 4]);
      float av[4] = {a.x, a.y, a.z, a.w};
      float bv[8] = {b0.x, b0.y, b0.z, b0.w, b1.x, b1.y, b1.z, b1.w};
      #pragma unroll
      for (int i = 0; i < 4; ++i)
        #pragma unroll
        for (int j = 0; j < 8; ++j) acc[i][j] += av[i] * bv[j];
    }
  }
  #pragma unroll
  for (int i = 0; i < 4; ++i) {
    const int grow = b * 128 + sbase + m0 + i;
    float nrm = 0.f;
    unsigned int hp[4], lp[4];
    #pragma unroll
    for (int j = 0; j < 8; j += 2) {
      float x0 = acc[i][j], x1 = acc[i][j + 1];
      nrm += x0 * x0 + x1 * x1;
      unsigned short h0 = f2bf(x0), h1 = f2bf(x1);
      unsigned short l0 = f2bf(x0 - bf2f(h0)), l1 = f2bf(x1 - bf2f(h1));
      hp[j >> 1] = h0 | ((unsigned)h1 << 16);
      lp[j >> 1] = l0 | ((unsigned)l1 << 16);
    }
    *reinterpret_cast<uint4*>(fg2 + (size_t)grow * 512 + n0)       = make_uint4(hp[0], hp[1], hp[2], hp[3]);
    *reinterpret_cast<uint4*>(fg2 + (size_t)grow * 512 + 256 + n0) = make_uint4(lp[0], lp[1], lp[2], lp[3]);
    #pragma unroll
    for (int msk = 1; msk <= 16; msk <<= 1) nrm += __shfl_xor(nrm, msk, 64);
    if (tn == 0) fgn[grow] = nrm;
  }
}

// ---------------- MFMA distance GEMM: 256x256 tile, 8 waves, phase schedule ----------------
// K_eff = 768 = 24 half-tiles of 32. LDS: 4 regions (A 16KB | B 16KB), 64B rows.
// Conflict-free XOR: slot = chunk ^ ((row>>1)&3)  -> every 8-lane group hits 8 distinct
// bank-quads on ds_read_b128. 3-deep prefetch, counted vmcnt(8). Non-temporal dist stores.
__global__ __launch_bounds__(512, 2) void k_dist(const unsigned short* __restrict__ fg2,
                                                 const unsigned short* __restrict__ fl2,
                                                 const float* __restrict__ fgn,
                                                 const float* __restrict__ fln,
                                                 float* __restrict__ out,
                                                 float* __restrict__ parts) {
  __shared__ __align__(16) char lds[4][32768];
  __shared__ float rn2s[256], cn2s[256];
  const int tid = threadIdx.x;
  const int w = tid >> 6, l = tid & 63;
  const int g = l >> 4, lr = l & 15;
  // grid 1280 = 8 XCD chunks of 160
  const int swz = (blockIdx.x & 7) * 160 + (blockIdx.x >> 3);
  const int mt = swz & 31, nt = swz >> 5;            // 32 x 40
  const int rbase = mt << 8, nbase = nt << 8;
  const int wm = (w >> 2) << 7;                      // 0 / 128
  const int wn = (w & 3) << 6;                       // 0,64,128,192

  if (tid < 256) { rn2s[tid] = fgn[rbase + tid]; cn2s[tid] = fln[nbase + tid]; }

  // staging source element-offsets (swizzled on the GLOBAL side; LDS stays linear)
  int baseA[2], baseB[2];
  #pragma unroll
  for (int t = 0; t < 2; ++t) {
    int p = (w * 2 + t) * 64 + l;       // chunk id 0..1023 (16B chunks of a 256x32 tile)
    int row = p >> 2, c = p & 3;
    int sw = (c ^ ((row >> 1) & 3)) << 3;
    baseA[t] = (rbase + row) * 512 + sw;
    baseB[t] = (nbase + row) * 512 + sw;
  }
  const int dstOff = w * 2048;          // per-wave LDS dest (2 x 1024B per half)

  // ds_read byte offsets within a region (A at 0, B at 16384); row stride 64B, chunk XOR
  int offA[8], offB[4];
  #pragma unroll
  for (int i = 0; i < 8; ++i) { int r = wm + i * 16 + lr; offA[i] = r * 64 + ((g ^ ((r >> 1) & 3)) << 4); }
  #pragma unroll
  for (int j = 0; j < 4; ++j) { int r = wn + j * 16 + lr; offB[j] = 16384 + r * 64 + ((g ^ ((r >> 1) & 3)) << 4); }

  f4v acc[8][4];
  #pragma unroll
  for (int i = 0; i < 8; ++i)
    #pragma unroll
    for (int j = 0; j < 4; ++j) acc[i][j] = (f4v)0.f;

  // k offsets for half-tile h: kt = h>>1 (0..11), slice = h&1
  auto kAof = [](int h) { int kt = h >> 1; return ((kt & 3) << 6) + ((kt & 4) ? 256 : 0) + ((h & 1) << 5); };
  auto kBof = [](int h) { int kt = h >> 1; return ((kt & 3) << 6) + ((kt >= 8) ? 256 : 0) + ((h & 1) << 5); };

  auto stageA = [&](int dst, int src) {
    const int kA = kAof(src);
    char* base = &lds[dst][0] + dstOff;
    GLD16(fg2 + (baseA[0] + kA), base);
    GLD16(fg2 + (baseA[1] + kA), base + 1024);
  };
  auto stageB = [&](int dst, int src) {
    const int kB = kBof(src);
    char* base = &lds[dst][16384] + dstOff;
    GLD16(fl2 + (baseB[0] + kB), base);
    GLD16(fl2 + (baseB[1] + kB), base + 1024);
  };

  // prologue: stage half-tiles 0,1,2 (12 vm instrs); wait for tile 0 (vmcnt 8 = tiles 1,2 in flight)
  #pragma unroll
  for (int hh = 0; hh < 3; ++hh) { stageA(hh, hh); stageB(hh, hh); }
  asm volatile("s_waitcnt vmcnt(8)" ::: "memory");
  __builtin_amdgcn_s_barrier();

  s8v va[4], vb[4];
  for (int h = 0; h < 24; ++h) {
    const char* A = &lds[h & 3][0];
    const int dst = (h + 3) & 3;
    const int src = (h + 3 <= 23) ? (h + 3) : 23;   // dummy re-stage keeps vmcnt literal valid

    // ---- phase A: C rows wm..wm+63 ----
    #pragma unroll
    for (int i = 0; i < 4; ++i) va[i] = *reinterpret_cast<const s8v*>(A + offA[i]);
    #pragma unroll
    for (int j = 0; j < 4; ++j) vb[j] = *reinterpret_cast<const s8v*>(A + offB[j]);
    stageA(dst, src);
    __builtin_amdgcn_s_barrier();
    asm volatile("s_waitcnt lgkmcnt(0)" ::: "memory");
    __builtin_amdgcn_sched_barrier(0);
    __builtin_amdgcn_s_setprio(1);
    #pragma unroll
    for (int i = 0; i < 4; ++i)
      #pragma unroll
      for (int j = 0; j < 4; ++j)
        acc[i][j] = __builtin_amdgcn_mfma_f32_16x16x32_bf16(va[i], vb[j], acc[i][j], 0, 0, 0);
    __builtin_amdgcn_s_setprio(0);
    __builtin_amdgcn_s_barrier();

    // ---- phase B: C rows wm+64..wm+127 (reuse vb) ----
    #pragma unroll
    for (int i = 0; i < 4; ++i) va[i] = *reinterpret_cast<const s8v*>(A + offA[4 + i]);
    stageB(dst, src);
    asm volatile("s_waitcnt vmcnt(8)" ::: "memory");   // half-tile h+1 fully landed (per-wave)
    __builtin_amdgcn_s_barrier();
    asm volatile("s_waitcnt lgkmcnt(0)" ::: "memory");
    __builtin_amdgcn_sched_barrier(0);
    __builtin_amdgcn_s_setprio(1);
    #pragma unroll
    for (int i = 0; i < 4; ++i)
      #pragma unroll
      for (int j = 0; j < 4; ++j)
        acc[4 + i][j] = __builtin_amdgcn_mfma_f32_16x16x32_bf16(va[i], vb[j], acc[4 + i][j], 0, 0, 0);
    __builtin_amdgcn_s_setprio(0);
    __builtin_amdgcn_s_barrier();
  }

  // drain all outstanding staging before reusing LDS as scratch
  asm volatile("s_waitcnt vmcnt(0)" ::: "memory");
  __builtin_amdgcn_s_barrier();

  // ---- epilogue: dist, nt-store, per-row stats over this block's 256 cols ----
  float cn[4];
  #pragma unroll
  for (int j = 0; j < 4; ++j) cn[j] = cn2s[wn + (j << 4) + lr];
  float* scr = reinterpret_cast<float*>(&lds[0][0]);   // 256 rows x 4 wavecols x 4 floats = 16KB

  #pragma unroll
  for (int i = 0; i < 8; ++i) {
    #pragma unroll
    for (int r = 0; r < 4; ++r) {
      const int rowloc = wm + (i << 4) + (g << 2) + r;
      const float r2 = rn2s[rowloc];
      const size_t orow = (size_t)(rbase + rowloc) * NF + nbase;
      float dv[4];
      #pragma unroll
      for (int j = 0; j < 4; ++j) {
        const int cloc = wn + (j << 4) + lr;
        float d2 = r2 - 2.0f * acc[i][j][r] + cn[j];
        float d = sqrtf(fmaxf(d2, 0.f));
        dv[j] = d;
        if (nbase + cloc < NF) __builtin_nontemporal_store(d, &out[orow + cloc]);
      }
      float bd = dv[0]; int bn = nbase + wn + lr;
      #pragma unroll
      for (int j = 1; j < 4; ++j) {
        int col = nbase + wn + (j << 4) + lr;
        if (dv[j] < bd) { bd = dv[j]; bn = col; }
      }
      #pragma unroll
      for (int msk = 1; msk <= 8; msk <<= 1) {
        float od = __shfl_xor(bd, msk, 64);
        int   on = __shfl_xor(bn, msk, 64);
        if (od < bd || (od == bd && on < bn)) { bd = od; bn = on; }
      }
      float s = 0.f;
      #pragma unroll
      for (int j = 0; j < 4; ++j) s += __expf(bd - dv[j]);
      #pragma unroll
      for (int msk = 1; msk <= 8; msk <<= 1) s += __shfl_xor(s, msk, 64);
      if (lr == 0) {
        float* q = scr + (rowloc << 4) + ((w & 3) << 2);
        q[0] = bd; q[1] = s; q[2] = (float)bn;
      }
    }
  }
  __syncthreads();
  if (tid < 256) {
    const float* q = scr + (tid << 4);
    float M = q[0], bn = q[2];
    #pragma unroll
    for (int c = 1; c < 4; ++c)
      if (q[c * 4] < M) { M = q[c * 4]; bn = q[c * 4 + 2]; }
    float S = 0.f;
    #pragma unroll
    for (int c = 0; c < 4; ++c) S += q[c * 4 + 1] * __expf(M - q[c * 4]);
    float* p = parts + (((size_t)(rbase + tid)) * 40 + nt) * 4;
    p[0] = M; p[1] = S; p[2] = M; p[3] = bn;
  }
}

// ---------------- combine 40 strips -> LSE + preds, then logp = -d - LSE ----------------
__global__ __launch_bounds__(256) void k_final(const float* __restrict__ parts,
                                               float* __restrict__ out) {
  const int row = blockIdx.x;
  __shared__ float sm[40][4];
  __shared__ float shL;
  const int t = threadIdx.x;
  if (t < 40)
    *reinterpret_cast<float4*>(sm[t]) =
        *reinterpret_cast<const float4*>(parts + ((size_t)row * 40 + t) * 4);
  __syncthreads();
  if (t == 0) {
    float m = FLT_MAX;
    for (int s = 0; s < 40; ++s) m = fminf(m, sm[s][0]);
    float S = 0.f;
    for (int s = 0; s < 40; ++s) S += sm[s][1] * __expf(m - sm[s][0]);
    float bd = FLT_MAX, bn = 0.f;
    for (int s = 0; s < 40; ++s) {
      float dd = sm[s][2], nn = sm[s][3];
      if (dd < bd || (dd == bd && nn < bn)) { bd = dd; bn = nn; }
    }
    shL = logf(S) - m;
    out[(size_t)ROWS * NF + row] = bn;        // preds
  }
  __syncthreads();
  const float L = shL;
  f4v* prow = reinterpret_cast<f4v*>(out + (size_t)row * NF);
  for (int c = t; c < 2500; c += 256) {
    f4v v = __builtin_nontemporal_load(prow + c);
    v = -v - L;
    __builtin_nontemporal_store(v, prow + c);
  }
}

extern "C" void kernel_launch(void* const* d_in, const int* in_sizes, int n_in,
                              void* d_out, int out_size, void* d_ws, size_t ws_size,
                              hipStream_t stream) {
  const int*   roles   = (const int*)d_in[0];
  const float* hidden  = (const float*)d_in[1];
  const float* filler  = (const float*)d_in[2];
  const float* roleemb = (const float*)d_in[3];
  const float* W       = (const float*)d_in[4];
  const float* bias    = (const float*)d_in[5];
  float* out = (float*)d_out;

  float* ws = (float*)d_ws;
  float*          ht    = ws;                               // 4,194,304 f32
  unsigned short* fg2   = (unsigned short*)(ws + 4194304);  // 8192 x 512 bf16
  unsigned short* fl2   = (unsigned short*)(ws + 6291456);  // 10240 x 512 bf16
  float*          fgn   = ws + 8912896;                     // 8192
  float*          fln   = fgn + 8192;                       // 10240 (pad=1e30)
  float*          parts = fln + 10240;                      // 8192 x 40 x 4

  k_cvt_filler<<<2560, 256, 0, stream>>>(filler, fl2, fln);
  k_gemm1<<<512, 256, 0, stream>>>(hidden, W, bias, ht);
  k_fg2<<<256, 256, 0, stream>>>(roles, roleemb, ht, fg2, fgn);
  k_dist<<<1280, 512, 0, stream>>>(fg2, fl2, fgn, fln, out, parts);
  k_final<<<8192, 256, 0, stream>>>(parts, out);
}